// Round 5
// baseline (563.202 us; speedup 1.0000x reference)
//
#include <hip/hip_runtime.h>
#include <math.h>

#define N_RNA 4096
#define N_ATAC 8192
#define IN_C 256
#define HID 128
#define NH 2
#define TOPK 10
#define CAP 32
#define TAU_EPS 0.12f
#define NEG_INF -3.402823466e38f

typedef __attribute__((ext_vector_type(8))) short bf16x8;
typedef __attribute__((ext_vector_type(4))) float f32x4;

static __device__ __forceinline__ f32x4 mfma16(bf16x8 a, bf16x8 b, f32x4 c) {
    return __builtin_amdgcn_mfma_f32_16x16x32_bf16(a, b, c, 0, 0, 0);
}

static __device__ __forceinline__ unsigned short f2bf(float f) {
    unsigned int u = __float_as_uint(f);
    unsigned int r = (u + 0x7fffu + ((u >> 16) & 1u)) >> 16;   // RNE
    return (unsigned short)r;
}
static __device__ __forceinline__ float bf2f(unsigned short h) {
    return __uint_as_float(((unsigned int)h) << 16);
}

// ---------------------------------------------------------------- top-k insert
__device__ __forceinline__ void topk_insert(float (&tv)[10], int (&ti)[10],
                                            float &mn, int &ms, float lv, int a) {
#pragma unroll
    for (int s = 0; s < 10; ++s) {
        if (s == ms) { tv[s] = lv; ti[s] = a; }
    }
    mn = tv[0]; ms = 0;
#pragma unroll
    for (int s = 1; s < 10; ++s) {
        if (tv[s] < mn) { mn = tv[s]; ms = s; }
    }
}

// ---------------------------------------------------------------- K0a: mask -> bits2[rt64][a][2]
__global__ __launch_bounds__(256) void prep_bits(
    const float* __restrict__ mask, unsigned int* __restrict__ bits2) {
    int bx = blockIdx.x;
    int rt = bx >> 5, ac = bx & 31;
    int a = ac * 256 + threadIdx.x;
    int r0 = rt * 64;
    unsigned int w0 = 0, w1 = 0;
#pragma unroll 8
    for (int rr = 0; rr < 32; ++rr) {
        float m0 = mask[(size_t)(r0 + rr) * N_ATAC + a];
        float m1 = mask[(size_t)(r0 + 32 + rr) * N_ATAC + a];
        w0 |= ((m0 > 0.5f) ? 1u : 0u) << rr;
        w1 |= ((m1 > 0.5f) ? 1u : 0u) << rr;
    }
    *(uint2*)&bits2[((size_t)rt * N_ATAC + a) * 2] = make_uint2(w0, w1);
}

// ---------------------------------------------------------------- K0b: zeros + fused weights
// [0,1024): zero atac_agg; [1024,1410): fuse weights
__global__ __launch_bounds__(256) void prep_misc(
    float* __restrict__ atac_agg,
    const float* __restrict__ Wor, const float* __restrict__ bor,
    const float* __restrict__ Woa, const float* __restrict__ boa,
    const float* __restrict__ Wsr, const float* __restrict__ bsr,
    const float* __restrict__ Wsa, const float* __restrict__ bsa,
    const float* __restrict__ Wdr, const float* __restrict__ bdr,
    const float* __restrict__ Wda, const float* __restrict__ bda,
    float* __restrict__ Wr1, float* __restrict__ Wr2, float* __restrict__ br,
    float* __restrict__ Wa1, float* __restrict__ Wa2, float* __restrict__ ba) {
    int bx = blockIdx.x;
    if (bx < 1024) {
        int i = bx * 256 + threadIdx.x;
        *(float4*)&atac_agg[(size_t)i * 4] = make_float4(0.f, 0.f, 0.f, 0.f);
        return;
    }
    int f = (bx - 1024) * 256 + threadIdx.x;
    if (f < 16384) {
        int i = f >> 7, j = f & 127; float s = 0.f;
        for (int t = 0; t < 128; ++t) s += Wor[i * 128 + t] * Wdr[t * 128 + j];
        Wr1[f] = s;
    } else if (f < 49152) {
        int e = f - 16384; int i = e >> 7, j = e & 127; float s = 0.f;
        for (int t = 0; t < 128; ++t) s += Wsr[i * 128 + t] * Wdr[(128 + t) * 128 + j];
        Wr2[e] = s;
    } else if (f < 65536) {
        int e = f - 49152; int i = e >> 7, j = e & 127; float s = 0.f;
        for (int t = 0; t < 128; ++t) s += Woa[i * 128 + t] * Wda[t * 128 + j];
        Wa1[e] = s;
    } else if (f < 98304) {
        int e = f - 65536; int i = e >> 7, j = e & 127; float s = 0.f;
        for (int t = 0; t < 128; ++t) s += Wsa[i * 128 + t] * Wda[(128 + t) * 128 + j];
        Wa2[e] = s;
    } else if (f < 98432) {
        int j = f - 98304; float s = bdr[j];
        for (int t = 0; t < 128; ++t) s += bor[t] * Wdr[t * 128 + j] + bsr[t] * Wdr[(128 + t) * 128 + j];
        br[j] = s;
    } else if (f < 98560) {
        int j = f - 98432; float s = bda[j];
        for (int t = 0; t < 128; ++t) s += boa[t] * Wda[t * 128 + j] + bsa[t] * Wda[(128 + t) * 128 + j];
        ba[j] = s;
    }
}

// ---------------------------------------------------------------- K1: projections
// cfg 0: q -> bf16 hi/lo per-head rows [h][r][64]
// cfg 2: k -> bf16 hi/lo MFMA-fragment layout [h][at][kc][n][8]
// cfg 1/3: v_r / v_a fp32 rows
__global__ __launch_bounds__(256) void proj_gemm(
    const float* __restrict__ x_rna, const float* __restrict__ x_atac,
    const float* __restrict__ Wq, const float* __restrict__ bq,
    const float* __restrict__ Wk, const float* __restrict__ bk,
    const float* __restrict__ Wvr, const float* __restrict__ bvr,
    const float* __restrict__ Wva, const float* __restrict__ bva,
    unsigned short* __restrict__ qhi, unsigned short* __restrict__ qlo,
    unsigned short* __restrict__ khf_hi, unsigned short* __restrict__ khf_lo,
    float* __restrict__ v_r, float* __restrict__ v_a) {
    int cfg = blockIdx.y;
    const float *X, *W, *B; int M;
    if (cfg == 0)      { X = x_rna;  W = Wq;  B = bq;  M = N_RNA;  }
    else if (cfg == 1) { X = x_rna;  W = Wvr; B = bvr; M = N_RNA;  }
    else if (cfg == 2) { X = x_atac; W = Wk;  B = bk;  M = N_ATAC; }
    else               { X = x_atac; W = Wva; B = bva; M = N_ATAC; }
    int r0 = blockIdx.x * 64;
    if (r0 >= M) return;

    __shared__ __align__(16) float x_s[64][33];
    __shared__ __align__(16) float w_s[32][128];
    int tid = threadIdx.x;
    int rg = tid >> 4, cg = tid & 15;

    float acc[4][8];
#pragma unroll
    for (int i = 0; i < 4; ++i)
#pragma unroll
        for (int j = 0; j < 8; ++j) acc[i][j] = 0.f;

    for (int k0 = 0; k0 < IN_C; k0 += 32) {
        __syncthreads();
        for (int i4 = tid; i4 < 512; i4 += 256) {
            int rr = i4 >> 3, kq = i4 & 7;
            float4 v = *(const float4*)&X[(size_t)(r0 + rr) * IN_C + k0 + kq * 4];
            x_s[rr][kq * 4 + 0] = v.x; x_s[rr][kq * 4 + 1] = v.y;
            x_s[rr][kq * 4 + 2] = v.z; x_s[rr][kq * 4 + 3] = v.w;
        }
        for (int i4 = tid; i4 < 1024; i4 += 256) {
            int kk = i4 >> 5, cq = i4 & 31;
            float4 v = *(const float4*)&W[(size_t)(k0 + kk) * HID + cq * 4];
            *(float4*)&w_s[kk][cq * 4] = v;
        }
        __syncthreads();
#pragma unroll 8
        for (int kk = 0; kk < 32; ++kk) {
            float x0 = x_s[rg * 4 + 0][kk], x1 = x_s[rg * 4 + 1][kk];
            float x2 = x_s[rg * 4 + 2][kk], x3 = x_s[rg * 4 + 3][kk];
            float4 wa = *(const float4*)&w_s[kk][cg * 4];
            float4 wb = *(const float4*)&w_s[kk][64 + cg * 4];
            acc[0][0] += x0 * wa.x; acc[0][1] += x0 * wa.y; acc[0][2] += x0 * wa.z; acc[0][3] += x0 * wa.w;
            acc[0][4] += x0 * wb.x; acc[0][5] += x0 * wb.y; acc[0][6] += x0 * wb.z; acc[0][7] += x0 * wb.w;
            acc[1][0] += x1 * wa.x; acc[1][1] += x1 * wa.y; acc[1][2] += x1 * wa.z; acc[1][3] += x1 * wa.w;
            acc[1][4] += x1 * wb.x; acc[1][5] += x1 * wb.y; acc[1][6] += x1 * wb.z; acc[1][7] += x1 * wb.w;
            acc[2][0] += x2 * wa.x; acc[2][1] += x2 * wa.y; acc[2][2] += x2 * wa.z; acc[2][3] += x2 * wa.w;
            acc[2][4] += x2 * wb.x; acc[2][5] += x2 * wb.y; acc[2][6] += x2 * wb.z; acc[2][7] += x2 * wb.w;
            acc[3][0] += x3 * wa.x; acc[3][1] += x3 * wa.y; acc[3][2] += x3 * wa.z; acc[3][3] += x3 * wa.w;
            acc[3][4] += x3 * wb.x; acc[3][5] += x3 * wb.y; acc[3][6] += x3 * wb.z; acc[3][7] += x3 * wb.w;
        }
    }
    float bv[8];
#pragma unroll
    for (int j = 0; j < 8; ++j) {
        int c = (j < 4) ? (cg * 4 + j) : (64 + cg * 4 + (j - 4));
        bv[j] = B[c];
    }
    if (cfg == 0 || cfg == 2) {
#pragma unroll
        for (int i = 0; i < 4; ++i) {
            int r = r0 + rg * 4 + i;
            float va[8];
#pragma unroll
            for (int j = 0; j < 8; ++j) va[j] = acc[i][j] + bv[j];
            ushort4 h0, l0, h1, l1;
            h0.x = f2bf(va[0]); h0.y = f2bf(va[1]); h0.z = f2bf(va[2]); h0.w = f2bf(va[3]);
            h1.x = f2bf(va[4]); h1.y = f2bf(va[5]); h1.z = f2bf(va[6]); h1.w = f2bf(va[7]);
            l0.x = f2bf(va[0] - bf2f(h0.x)); l0.y = f2bf(va[1] - bf2f(h0.y));
            l0.z = f2bf(va[2] - bf2f(h0.z)); l0.w = f2bf(va[3] - bf2f(h0.w));
            l1.x = f2bf(va[4] - bf2f(h1.x)); l1.y = f2bf(va[5] - bf2f(h1.y));
            l1.z = f2bf(va[6] - bf2f(h1.z)); l1.w = f2bf(va[7] - bf2f(h1.w));
            if (cfg == 0) {
                size_t o0 = (size_t)r * 64 + cg * 4;                 // head 0
                size_t o1 = (size_t)(N_RNA + r) * 64 + cg * 4;       // head 1
                *(ushort4*)&qhi[o0] = h0; *(ushort4*)&qhi[o1] = h1;
                *(ushort4*)&qlo[o0] = l0; *(ushort4*)&qlo[o1] = l1;
            } else {
                int at = r >> 4, n = r & 15;
                int kc = cg >> 1, e = (cg & 1) * 4;
                size_t o0 = ((size_t)(at) * 8 + kc) * 128 + n * 8 + e;          // head 0
                size_t o1 = ((size_t)(512 + at) * 8 + kc) * 128 + n * 8 + e;    // head 1
                *(ushort4*)&khf_hi[o0] = h0; *(ushort4*)&khf_hi[o1] = h1;
                *(ushort4*)&khf_lo[o0] = l0; *(ushort4*)&khf_lo[o1] = l1;
            }
        }
    } else {
        float* C = (cfg == 1) ? v_r : v_a;
#pragma unroll
        for (int i = 0; i < 4; ++i) {
            int r = r0 + rg * 4 + i;
            float4 oa = make_float4(acc[i][0] + bv[0], acc[i][1] + bv[1], acc[i][2] + bv[2], acc[i][3] + bv[3]);
            float4 ob = make_float4(acc[i][4] + bv[4], acc[i][5] + bv[5], acc[i][6] + bv[6], acc[i][7] + bv[7]);
            *(float4*)&C[(size_t)r * HID + cg * 4] = oa;
            *(float4*)&C[(size_t)r * HID + 64 + cg * 4] = ob;
        }
    }
}

// ---------------------------------------------------------------- K2: two-phase MFMA attention (fragment-direct)
// grid (64 rtiles, 16 = h*8+chunk), block 256 (4 waves, 4 blocks/CU).
// Each block: 64 rows x 1024 a.  Phase A: approx (hi*hi) bucket maxes ->
// tau = 10th bucket max - slack.  Phase B: exact 3-pass, survivors -> LDS lists.
__global__ __launch_bounds__(256, 4) void attn2(
    const unsigned short* __restrict__ qhi, const unsigned short* __restrict__ qlo,
    const unsigned short* __restrict__ khf_hi, const unsigned short* __restrict__ khf_lo,
    const unsigned int* __restrict__ bits2,
    int* __restrict__ scnt, float* __restrict__ sval, int* __restrict__ sidx) {
    int rt = blockIdx.x; int r0 = rt * 64;
    int hq = blockIdx.y; int h = hq >> 3, chunk = hq & 7;
    int tid = threadIdx.x;
    int w = tid >> 6, lane = tid & 63;
    int n = lane & 15, quad = lane >> 4;
    int q4 = quad * 4;
    int at0 = chunk * 64 + w * 16;          // a-tile base (16 a per tile)
    int hbase = h * 512;

    __shared__ float bmax[64][65];
    __shared__ float taus[64];
    __shared__ int   lcnt[64];
    __shared__ float lval[64][CAP];
    __shared__ int   lidx[64][CAP];

    const bf16x8* kh8 = (const bf16x8*)khf_hi;
    const bf16x8* kl8 = (const bf16x8*)khf_lo;
    const uint2* b2 = (const uint2*)bits2;

    // Preload A-frags: 4 m-tiles x 2 k-chunks, hi+lo
    bf16x8 Ah[4][2], Al[4][2];
#pragma unroll
    for (int mt = 0; mt < 4; ++mt)
#pragma unroll
        for (int c = 0; c < 2; ++c) {
            size_t off = ((size_t)h * N_RNA + r0 + mt * 16 + n) * 64 + c * 32 + quad * 8;
            Ah[mt][c] = *(const bf16x8*)(qhi + off);
            Al[mt][c] = *(const bf16x8*)(qlo + off);
        }

    float mx[4][4];
#pragma unroll
    for (int mt = 0; mt < 4; ++mt)
#pragma unroll
        for (int i = 0; i < 4; ++i) mx[mt][i] = 0.f;

    // ---------------- phase A: approximate (hi*hi) bucket maxes ----------------
#pragma unroll 2
    for (int t = 0; t < 16; ++t) {
        int at = at0 + t;
        size_t bidx = ((size_t)hbase + at) * 128 + lane;
        bf16x8 Bh0 = kh8[bidx];
        bf16x8 Bh1 = kh8[bidx + 64];
        uint2 bl = b2[(size_t)rt * N_ATAC + at * 16 + n];

        f32x4 S[4];
#pragma unroll
        for (int mt = 0; mt < 4; ++mt) {
            f32x4 s = {0.f, 0.f, 0.f, 0.f};
            s = mfma16(Ah[mt][0], Bh0, s);
            s = mfma16(Ah[mt][1], Bh1, s);
            S[mt] = s;
        }
#pragma unroll
        for (int mt = 0; mt < 4; ++mt) {
            unsigned int bw = (mt < 2) ? bl.x : bl.y;
            unsigned int sh = bw >> (((mt & 1) << 4) + q4);
#pragma unroll
            for (int i = 0; i < 4; ++i) {
                float v = ((sh >> i) & 1) ? S[mt][i] : 0.f;
                mx[mt][i] = fmaxf(mx[mt][i], v);
            }
        }
    }

    {
        int b = w * 16 + n;
#pragma unroll
        for (int mt = 0; mt < 4; ++mt)
#pragma unroll
            for (int i = 0; i < 4; ++i) bmax[mt * 16 + q4 + i][b] = mx[mt][i];
    }
    __syncthreads();
    if (tid < 64) {
        int row = tid;
        float t10 = 0.f;
        for (int pass = 0; pass < 10; ++pass) {
            float best = -1.f; int bj = 0;
            for (int j = 0; j < 64; ++j) {
                float v = bmax[row][j];
                if (v > best) { best = v; bj = j; }
            }
            bmax[row][bj] = -1.f;
            t10 = best;
        }
        taus[row] = t10 - TAU_EPS;
    } else if (tid < 128) {
        lcnt[tid - 64] = 0;
    }
    __syncthreads();

    float tau[4][4];
#pragma unroll
    for (int mt = 0; mt < 4; ++mt)
#pragma unroll
        for (int i = 0; i < 4; ++i) tau[mt][i] = taus[mt * 16 + q4 + i];

    // ---------------- phase B: exact scores, collect survivors ----------------
#pragma unroll 2
    for (int t = 0; t < 16; ++t) {
        int at = at0 + t;
        size_t bidx = ((size_t)hbase + at) * 128 + lane;
        bf16x8 Bh0 = kh8[bidx];
        bf16x8 Bh1 = kh8[bidx + 64];
        bf16x8 Bl0 = kl8[bidx];
        bf16x8 Bl1 = kl8[bidx + 64];
        uint2 bl = b2[(size_t)rt * N_ATAC + at * 16 + n];

        f32x4 S[4];
#pragma unroll
        for (int mt = 0; mt < 4; ++mt) {
            f32x4 s = {0.f, 0.f, 0.f, 0.f};
            s = mfma16(Ah[mt][0], Bh0, s);
            s = mfma16(Ah[mt][1], Bh1, s);
            s = mfma16(Ah[mt][0], Bl0, s);
            s = mfma16(Ah[mt][1], Bl1, s);
            s = mfma16(Al[mt][0], Bh0, s);
            s = mfma16(Al[mt][1], Bh1, s);
            S[mt] = s;
        }
        int a16 = at * 16 + n;
#pragma unroll
        for (int mt = 0; mt < 4; ++mt) {
            unsigned int bw = (mt < 2) ? bl.x : bl.y;
            unsigned int sh = bw >> (((mt & 1) << 4) + q4);
#pragma unroll
            for (int i = 0; i < 4; ++i) {
                if (((sh >> i) & 1) && S[mt][i] >= tau[mt][i]) {
                    int row = mt * 16 + q4 + i;
                    int pos = atomicAdd(&lcnt[row], 1);
                    if (pos < CAP) { lval[row][pos] = S[mt][i]; lidx[row][pos] = a16; }
                }
            }
        }
    }
    __syncthreads();

    // bulk write: block exclusively owns slot ((h*4096 + r)*8 + chunk)
    if (tid < 64) {
        int c = lcnt[tid]; if (c > CAP) c = CAP;
        scnt[((size_t)h * N_RNA + r0 + tid) * 8 + chunk] = c;
    }
    {
        int row = tid >> 2, j0 = tid & 3;
        int c = lcnt[row]; if (c > CAP) c = CAP;
        size_t slot = ((size_t)h * N_RNA + r0 + row) * 8 + chunk;
        for (int j = j0; j < c; j += 4) {
            sval[slot * CAP + j] = lval[row][j];
            sidx[slot * CAP + j] = lidx[row][j];
        }
    }
}

// ---------------------------------------------------------------- K3: merge survivors + sigmoid + softmax + threshold
__global__ __launch_bounds__(64) void topk_finalize(
    const int* __restrict__ scnt, const float* __restrict__ sval, const int* __restrict__ sidx,
    float* __restrict__ sel_w, int* __restrict__ sel_i) {
    int p = blockIdx.x * 64 + threadIdx.x;
    if (p >= NH * N_RNA) return;
    float mv[10]; int mi[10];
#pragma unroll
    for (int s = 0; s < 10; ++s) { mv[s] = NEG_INF; mi[s] = 0; }
    float mn = NEG_INF; int ms = 0;
    for (int q = 0; q < 8; ++q) {
        size_t slot = (size_t)p * 8 + q;
        int c = scnt[slot]; if (c > CAP) c = CAP;
        for (int j = 0; j < c; ++j) {
            float v = sval[slot * CAP + j];
            if (v > mn) topk_insert(mv, mi, mn, ms, v, sidx[slot * CAP + j]);
        }
    }
    float sg[10]; float es[10]; float sum = 0.f;
#pragma unroll
    for (int s = 0; s < 10; ++s) {
        sg[s] = 1.0f / (1.0f + expf(-mv[s]));
        es[s] = expf(sg[s]);
        sum += es[s];
    }
    float inv = 1.0f / sum;
    int base = p * 16;
#pragma unroll
    for (int s = 0; s < 10; ++s) {
        float w = es[s] * inv;
        if (!(sg[s] > 0.8f)) w = 0.f;
        sel_w[base + s] = w;
        sel_i[base + s] = mi[s];
    }
}

// ---------------------------------------------------------------- K4a: rna_agg gather
__global__ __launch_bounds__(256) void rna_gather(
    const float* __restrict__ sel_w, const int* __restrict__ sel_i,
    const float* __restrict__ v_a, float* __restrict__ rna_agg) {
    int gid = blockIdx.x * 256 + threadIdx.x;
    int r = gid >> 4, g = gid & 15;
    int c0 = g * 8; int h = g >> 3;
    int base = (h * N_RNA + r) * 16;
    float4 a0 = make_float4(0.f, 0.f, 0.f, 0.f);
    float4 a1 = make_float4(0.f, 0.f, 0.f, 0.f);
    for (int i = 0; i < TOPK; ++i) {
        float w = sel_w[base + i];
        int idx = sel_i[base + i];
        const float4* vp = (const float4*)(v_a + (size_t)idx * HID + c0);
        float4 v0 = vp[0], v1 = vp[1];
        a0.x += w * v0.x; a0.y += w * v0.y; a0.z += w * v0.z; a0.w += w * v0.w;
        a1.x += w * v1.x; a1.y += w * v1.y; a1.z += w * v1.z; a1.w += w * v1.w;
    }
    float4* op = (float4*)(rna_agg + (size_t)r * HID + c0);
    op[0] = a0; op[1] = a1;
}

// ---------------------------------------------------------------- K4b: atac_agg scatter (atomics)
__global__ __launch_bounds__(256) void atac_scatter(
    const float* __restrict__ sel_w, const int* __restrict__ sel_i,
    const float* __restrict__ v_r, float* __restrict__ atac_agg) {
    int wid = threadIdx.x >> 6, lane = threadIdx.x & 63;
    int p = blockIdx.x * 4 + wid;
    int h = p >> 12; int r = p & 4095;
    float v = v_r[(size_t)r * HID + h * 64 + lane];
    int base = p * 16;
    for (int i = 0; i < TOPK; ++i) {
        float w = sel_w[base + i];
        if (w != 0.f) {
            int idx = sel_i[base + i];
            atomicAdd(&atac_agg[(size_t)idx * HID + h * 64 + lane], w * v);
        }
    }
}

// ---------------------------------------------------------------- K5: C = A@W1 + X@W2 + bias (both outputs)
__global__ __launch_bounds__(256) void out_gemm(
    const float* __restrict__ rna_agg, const float* __restrict__ x_rna,
    const float* __restrict__ Wr1, const float* __restrict__ Wr2, const float* __restrict__ brf,
    const float* __restrict__ atac_agg, const float* __restrict__ x_atac,
    const float* __restrict__ Wa1, const float* __restrict__ Wa2, const float* __restrict__ baf,
    float* __restrict__ out_r, float* __restrict__ out_a) {
    int bx = blockIdx.x;
    const float *A, *X, *W1, *W2, *bias; float* C;
    int rb;
    if (bx < 512) { A = rna_agg; X = x_rna; W1 = Wr1; W2 = Wr2; bias = brf; C = out_r; rb = bx; }
    else { A = atac_agg; X = x_atac; W1 = Wa1; W2 = Wa2; bias = baf; C = out_a; rb = bx - 512; }
    int r = rb * 8 + (threadIdx.x >> 5);
    int cg = threadIdx.x & 31; int c0 = cg * 4;
    float4 acc = *(const float4*)&bias[c0];
    const float* a = A + (size_t)r * HID;
#pragma unroll 4
    for (int k = 0; k < 128; ++k) {
        float av = a[k];
        float4 w = *(const float4*)&W1[(size_t)k * HID + c0];
        acc.x += av * w.x; acc.y += av * w.y; acc.z += av * w.z; acc.w += av * w.w;
    }
    const float* x = X + (size_t)r * IN_C;
#pragma unroll 4
    for (int k = 0; k < 256; ++k) {
        float xv = x[k];
        float4 w = *(const float4*)&W2[(size_t)k * HID + c0];
        acc.x += xv * w.x; acc.y += xv * w.y; acc.z += xv * w.z; acc.w += xv * w.w;
    }
    *(float4*)&C[(size_t)r * HID + c0] = acc;
}

// ---------------------------------------------------------------- launch
extern "C" void kernel_launch(void* const* d_in, const int* in_sizes, int n_in,
                              void* d_out, int out_size, void* d_ws, size_t ws_size,
                              hipStream_t stream) {
    const float* x_rna = (const float*)d_in[0];
    const float* x_atac = (const float*)d_in[1];
    const float* mask = (const float*)d_in[2];
    const float* Wq = (const float*)d_in[3];  const float* bq = (const float*)d_in[4];
    const float* Wk = (const float*)d_in[5];  const float* bk = (const float*)d_in[6];
    const float* Wvr = (const float*)d_in[7]; const float* bvr = (const float*)d_in[8];
    const float* Wva = (const float*)d_in[9]; const float* bva = (const float*)d_in[10];
    const float* Wor = (const float*)d_in[11]; const float* bor = (const float*)d_in[12];
    const float* Woa = (const float*)d_in[13]; const float* boa = (const float*)d_in[14];
    const float* Wsr = (const float*)d_in[15]; const float* bsr = (const float*)d_in[16];
    const float* Wsa = (const float*)d_in[17]; const float* bsa = (const float*)d_in[18];
    const float* Wdr = (const float*)d_in[19]; const float* bdr = (const float*)d_in[20];
    const float* Wda = (const float*)d_in[21]; const float* bda = (const float*)d_in[22];

    float* out_r = (float*)d_out;
    float* out_a = out_r + N_RNA * HID;

    float* ws = (float*)d_ws;
    unsigned short* qhi = (unsigned short*)ws;            // 2*4096*64 us
    unsigned short* qlo = qhi + 524288;
    unsigned short* khf_hi = qlo + 524288;                // 2*8192*64 us (frag layout)
    unsigned short* khf_lo = khf_hi + 1048576;
    unsigned int* bits2 = (unsigned int*)(ws + 1572864);  // 64*8192*2 uint
    float* v_r = ws + 1572864 + 1048576;                  // 4096x128
    float* v_a = v_r + 524288;                            // 8192x128
    float* Wr1 = v_a + 1048576;                           // 128x128
    float* Wr2 = Wr1 + 16384;                             // 256x128
    float* brf = Wr2 + 32768;                             // 128
    float* Wa1 = brf + 128;                               // 128x128
    float* Wa2 = Wa1 + 16384;                             // 256x128
    float* baf = Wa2 + 32768;                             // 128
    int* scnt = (int*)(baf + 128);                        // 8192*8 ints
    float* sval = (float*)scnt + 65536;                   // 65536*32
    int* sidx = (int*)(sval + 2097152);                   // 65536*32
    float* sel_w = (float*)sidx + 2097152;                // 8192*16
    int* sel_i = (int*)(sel_w + 131072);                  // 8192*16
    float* rna_agg = (float*)sel_i + 131072;              // 4096x128
    float* atac_agg = rna_agg + 524288;                   // 8192x128

    hipLaunchKernelGGL(prep_bits, dim3(2048), dim3(256), 0, stream, mask, bits2);
    hipLaunchKernelGGL(prep_misc, dim3(1410), dim3(256), 0, stream,
                       atac_agg,
                       Wor, bor, Woa, boa, Wsr, bsr, Wsa, bsa, Wdr, bdr, Wda, bda,
                       Wr1, Wr2, brf, Wa1, Wa2, baf);
    hipLaunchKernelGGL(proj_gemm, dim3(128, 4), dim3(256), 0, stream,
                       x_rna, x_atac, Wq, bq, Wk, bk, Wvr, bvr, Wva, bva,
                       qhi, qlo, khf_hi, khf_lo, v_r, v_a);
    hipLaunchKernelGGL(attn2, dim3(64, 16), dim3(256), 0, stream,
                       qhi, qlo, khf_hi, khf_lo, bits2, scnt, sval, sidx);
    hipLaunchKernelGGL(topk_finalize, dim3(128), dim3(64), 0, stream,
                       scnt, sval, sidx, sel_w, sel_i);
    hipLaunchKernelGGL(rna_gather, dim3(256), dim3(256), 0, stream, sel_w, sel_i, v_a, rna_agg);
    hipLaunchKernelGGL(atac_scatter, dim3(2048), dim3(256), 0, stream, sel_w, sel_i, v_r, atac_agg);
    hipLaunchKernelGGL(out_gemm, dim3(1536), dim3(256), 0, stream,
                       rna_agg, x_rna, Wr1, Wr2, brf,
                       atac_agg, x_atac, Wa1, Wa2, baf, out_r, out_a);
}

// Round 6
// 535.728 us; speedup vs baseline: 1.0513x; 1.0513x over previous
//
#include <hip/hip_runtime.h>
#include <math.h>

#define N_RNA 4096
#define N_ATAC 8192
#define IN_C 256
#define HID 128
#define NH 2
#define TOPK 10
#define CAP 32
#define NCHUNK 8
#define TAU_EPS 0.12f
#define NEG_INF -3.402823466e38f

typedef __attribute__((ext_vector_type(8))) short bf16x8;
typedef __attribute__((ext_vector_type(4))) float f32x4;

static __device__ __forceinline__ f32x4 mfma16(bf16x8 a, bf16x8 b, f32x4 c) {
    return __builtin_amdgcn_mfma_f32_16x16x32_bf16(a, b, c, 0, 0, 0);
}

static __device__ __forceinline__ unsigned short f2bf(float f) {
    unsigned int u = __float_as_uint(f);
    unsigned int r = (u + 0x7fffu + ((u >> 16) & 1u)) >> 16;   // RNE
    return (unsigned short)r;
}
static __device__ __forceinline__ float bf2f(unsigned short h) {
    return __uint_as_float(((unsigned int)h) << 16);
}

// ---------------------------------------------------------------- K0: prep_all (block-ranged)
// [0,2048): mask->bits2.  [2048,3072): zero atac_agg.  [3072,3458): fuse weights.
// [3458,3842): projections (cfg0 q:64, cfg1 v_r:64, cfg2 k:128, cfg3 v_a:128 blocks).
__global__ __launch_bounds__(256) void prep_all(
    const float* __restrict__ mask, unsigned int* __restrict__ bits2,
    float* __restrict__ atac_agg,
    const float* __restrict__ Wor, const float* __restrict__ bor,
    const float* __restrict__ Woa, const float* __restrict__ boa,
    const float* __restrict__ Wsr, const float* __restrict__ bsr,
    const float* __restrict__ Wsa, const float* __restrict__ bsa,
    const float* __restrict__ Wdr, const float* __restrict__ bdr,
    const float* __restrict__ Wda, const float* __restrict__ bda,
    float* __restrict__ Wr1, float* __restrict__ Wr2, float* __restrict__ br,
    float* __restrict__ Wa1, float* __restrict__ Wa2, float* __restrict__ ba,
    const float* __restrict__ x_rna, const float* __restrict__ x_atac,
    const float* __restrict__ Wq, const float* __restrict__ bq,
    const float* __restrict__ Wk, const float* __restrict__ bk,
    const float* __restrict__ Wvr, const float* __restrict__ bvr,
    const float* __restrict__ Wva, const float* __restrict__ bva,
    unsigned short* __restrict__ qhi, unsigned short* __restrict__ qlo,
    unsigned short* __restrict__ khf_hi, unsigned short* __restrict__ khf_lo,
    float* __restrict__ v_r, float* __restrict__ v_a) {
    __shared__ __align__(16) float x_s[64][33];
    __shared__ __align__(16) float w_s[32][128];
    int bx = blockIdx.x;
    int tid = threadIdx.x;

    if (bx < 2048) {                              // ---- mask -> bits2
        int rt = bx >> 5, ac = bx & 31;
        int a = ac * 256 + tid;
        int r0 = rt * 64;
        unsigned int w0 = 0, w1 = 0;
#pragma unroll 8
        for (int rr = 0; rr < 32; ++rr) {
            float m0 = mask[(size_t)(r0 + rr) * N_ATAC + a];
            float m1 = mask[(size_t)(r0 + 32 + rr) * N_ATAC + a];
            w0 |= ((m0 > 0.5f) ? 1u : 0u) << rr;
            w1 |= ((m1 > 0.5f) ? 1u : 0u) << rr;
        }
        *(uint2*)&bits2[((size_t)rt * N_ATAC + a) * 2] = make_uint2(w0, w1);
        return;
    }
    if (bx < 3072) {                              // ---- zero atac_agg
        int i = (bx - 2048) * 256 + tid;
        *(float4*)&atac_agg[(size_t)i * 4] = make_float4(0.f, 0.f, 0.f, 0.f);
        return;
    }
    if (bx < 3458) {                              // ---- fuse weights
        int f = (bx - 3072) * 256 + tid;
        if (f < 16384) {
            int i = f >> 7, j = f & 127; float s = 0.f;
            for (int t = 0; t < 128; ++t) s += Wor[i * 128 + t] * Wdr[t * 128 + j];
            Wr1[f] = s;
        } else if (f < 49152) {
            int e = f - 16384; int i = e >> 7, j = e & 127; float s = 0.f;
            for (int t = 0; t < 128; ++t) s += Wsr[i * 128 + t] * Wdr[(128 + t) * 128 + j];
            Wr2[e] = s;
        } else if (f < 65536) {
            int e = f - 49152; int i = e >> 7, j = e & 127; float s = 0.f;
            for (int t = 0; t < 128; ++t) s += Woa[i * 128 + t] * Wda[t * 128 + j];
            Wa1[e] = s;
        } else if (f < 98304) {
            int e = f - 65536; int i = e >> 7, j = e & 127; float s = 0.f;
            for (int t = 0; t < 128; ++t) s += Wsa[i * 128 + t] * Wda[(128 + t) * 128 + j];
            Wa2[e] = s;
        } else if (f < 98432) {
            int j = f - 98304; float s = bdr[j];
            for (int t = 0; t < 128; ++t) s += bor[t] * Wdr[t * 128 + j] + bsr[t] * Wdr[(128 + t) * 128 + j];
            br[j] = s;
        } else if (f < 98560) {
            int j = f - 98432; float s = bda[j];
            for (int t = 0; t < 128; ++t) s += boa[t] * Wda[t * 128 + j] + bsa[t] * Wda[(128 + t) * 128 + j];
            ba[j] = s;
        }
        return;
    }

    // ---- projections
    int e = bx - 3458;
    int cfg, rblk;
    if (e < 64)       { cfg = 0; rblk = e; }
    else if (e < 128) { cfg = 1; rblk = e - 64; }
    else if (e < 256) { cfg = 2; rblk = e - 128; }
    else              { cfg = 3; rblk = e - 256; }
    const float *X, *W, *B;
    if (cfg == 0)      { X = x_rna;  W = Wq;  B = bq;  }
    else if (cfg == 1) { X = x_rna;  W = Wvr; B = bvr; }
    else if (cfg == 2) { X = x_atac; W = Wk;  B = bk;  }
    else               { X = x_atac; W = Wva; B = bva; }
    int r0 = rblk * 64;
    int rg = tid >> 4, cg = tid & 15;

    float acc[4][8];
#pragma unroll
    for (int i = 0; i < 4; ++i)
#pragma unroll
        for (int j = 0; j < 8; ++j) acc[i][j] = 0.f;

    for (int k0 = 0; k0 < IN_C; k0 += 32) {
        __syncthreads();
        for (int i4 = tid; i4 < 512; i4 += 256) {
            int rr = i4 >> 3, kq = i4 & 7;
            float4 v = *(const float4*)&X[(size_t)(r0 + rr) * IN_C + k0 + kq * 4];
            x_s[rr][kq * 4 + 0] = v.x; x_s[rr][kq * 4 + 1] = v.y;
            x_s[rr][kq * 4 + 2] = v.z; x_s[rr][kq * 4 + 3] = v.w;
        }
        for (int i4 = tid; i4 < 1024; i4 += 256) {
            int kk = i4 >> 5, cq = i4 & 31;
            float4 v = *(const float4*)&W[(size_t)(k0 + kk) * HID + cq * 4];
            *(float4*)&w_s[kk][cq * 4] = v;
        }
        __syncthreads();
#pragma unroll 8
        for (int kk = 0; kk < 32; ++kk) {
            float x0 = x_s[rg * 4 + 0][kk], x1 = x_s[rg * 4 + 1][kk];
            float x2 = x_s[rg * 4 + 2][kk], x3 = x_s[rg * 4 + 3][kk];
            float4 wa = *(const float4*)&w_s[kk][cg * 4];
            float4 wb = *(const float4*)&w_s[kk][64 + cg * 4];
            acc[0][0] += x0 * wa.x; acc[0][1] += x0 * wa.y; acc[0][2] += x0 * wa.z; acc[0][3] += x0 * wa.w;
            acc[0][4] += x0 * wb.x; acc[0][5] += x0 * wb.y; acc[0][6] += x0 * wb.z; acc[0][7] += x0 * wb.w;
            acc[1][0] += x1 * wa.x; acc[1][1] += x1 * wa.y; acc[1][2] += x1 * wa.z; acc[1][3] += x1 * wa.w;
            acc[1][4] += x1 * wb.x; acc[1][5] += x1 * wb.y; acc[1][6] += x1 * wb.z; acc[1][7] += x1 * wb.w;
            acc[2][0] += x2 * wa.x; acc[2][1] += x2 * wa.y; acc[2][2] += x2 * wa.z; acc[2][3] += x2 * wa.w;
            acc[2][4] += x2 * wb.x; acc[2][5] += x2 * wb.y; acc[2][6] += x2 * wb.z; acc[2][7] += x2 * wb.w;
            acc[3][0] += x3 * wa.x; acc[3][1] += x3 * wa.y; acc[3][2] += x3 * wa.z; acc[3][3] += x3 * wa.w;
            acc[3][4] += x3 * wb.x; acc[3][5] += x3 * wb.y; acc[3][6] += x3 * wb.z; acc[3][7] += x3 * wb.w;
        }
    }
    float bv[8];
#pragma unroll
    for (int j = 0; j < 8; ++j) {
        int c = (j < 4) ? (cg * 4 + j) : (64 + cg * 4 + (j - 4));
        bv[j] = B[c];
    }
    if (cfg == 0 || cfg == 2) {
#pragma unroll
        for (int i = 0; i < 4; ++i) {
            int r = r0 + rg * 4 + i;
            float va[8];
#pragma unroll
            for (int j = 0; j < 8; ++j) va[j] = acc[i][j] + bv[j];
            ushort4 h0, l0, h1, l1;
            h0.x = f2bf(va[0]); h0.y = f2bf(va[1]); h0.z = f2bf(va[2]); h0.w = f2bf(va[3]);
            h1.x = f2bf(va[4]); h1.y = f2bf(va[5]); h1.z = f2bf(va[6]); h1.w = f2bf(va[7]);
            l0.x = f2bf(va[0] - bf2f(h0.x)); l0.y = f2bf(va[1] - bf2f(h0.y));
            l0.z = f2bf(va[2] - bf2f(h0.z)); l0.w = f2bf(va[3] - bf2f(h0.w));
            l1.x = f2bf(va[4] - bf2f(h1.x)); l1.y = f2bf(va[5] - bf2f(h1.y));
            l1.z = f2bf(va[6] - bf2f(h1.z)); l1.w = f2bf(va[7] - bf2f(h1.w));
            if (cfg == 0) {
                size_t o0 = (size_t)r * 64 + cg * 4;
                size_t o1 = (size_t)(N_RNA + r) * 64 + cg * 4;
                *(ushort4*)&qhi[o0] = h0; *(ushort4*)&qhi[o1] = h1;
                *(ushort4*)&qlo[o0] = l0; *(ushort4*)&qlo[o1] = l1;
            } else {
                int at = r >> 4, n = r & 15;
                int kc = cg >> 1, ee = (cg & 1) * 4;
                size_t o0 = ((size_t)(at) * 8 + kc) * 128 + n * 8 + ee;
                size_t o1 = ((size_t)(512 + at) * 8 + kc) * 128 + n * 8 + ee;
                *(ushort4*)&khf_hi[o0] = h0; *(ushort4*)&khf_hi[o1] = h1;
                *(ushort4*)&khf_lo[o0] = l0; *(ushort4*)&khf_lo[o1] = l1;
            }
        }
    } else {
        float* C = (cfg == 1) ? v_r : v_a;
#pragma unroll
        for (int i = 0; i < 4; ++i) {
            int r = r0 + rg * 4 + i;
            float4 oa = make_float4(acc[i][0] + bv[0], acc[i][1] + bv[1], acc[i][2] + bv[2], acc[i][3] + bv[3]);
            float4 ob = make_float4(acc[i][4] + bv[4], acc[i][5] + bv[5], acc[i][6] + bv[6], acc[i][7] + bv[7]);
            *(float4*)&C[(size_t)r * HID + cg * 4] = oa;
            *(float4*)&C[(size_t)r * HID + 64 + cg * 4] = ob;
        }
    }
}

// ---------------------------------------------------------------- K1: two-phase MFMA attention
// grid (128 rtiles of 32 rows, 16 = h*8+chunk), block 256 (4 waves, 8 blocks/CU).
// Each block: 32 rows x 1024 a.  Phase A: approx (hi*hi) bucket maxes ->
// tau = 10th bucket max - slack.  Phase B: exact 3-pass, survivors -> LDS lists.
__global__ __launch_bounds__(256, 8) void attn2(
    const unsigned short* __restrict__ qhi, const unsigned short* __restrict__ qlo,
    const unsigned short* __restrict__ khf_hi, const unsigned short* __restrict__ khf_lo,
    const unsigned int* __restrict__ bits2,
    int* __restrict__ scnt, float* __restrict__ sval, int* __restrict__ sidx) {
    int rt = blockIdx.x; int r0 = rt * 32;
    int hq = blockIdx.y; int h = hq >> 3, chunk = hq & 7;
    int tid = threadIdx.x;
    int w = tid >> 6, lane = tid & 63;
    int n = lane & 15, quad = lane >> 4;
    int q4 = quad * 4;
    int at0 = chunk * 64 + w * 16;          // a-tile base (16 a per tile)
    int hbase = h * 512;
    int rt64 = rt >> 1, word = rt & 1;

    __shared__ __align__(16) float smem[32 * 65];   // bmax [32][65]; reused: lval[32][32] | lidx[32][32]
    __shared__ float taus[32];
    __shared__ int   lcnt[32];

    const bf16x8* kh8 = (const bf16x8*)khf_hi;
    const bf16x8* kl8 = (const bf16x8*)khf_lo;

    // Preload A-frags: 2 m-tiles x 2 k-chunks, hi+lo
    bf16x8 Ah[2][2], Al[2][2];
#pragma unroll
    for (int mt = 0; mt < 2; ++mt)
#pragma unroll
        for (int c = 0; c < 2; ++c) {
            size_t off = ((size_t)h * N_RNA + r0 + mt * 16 + n) * 64 + c * 32 + quad * 8;
            Ah[mt][c] = *(const bf16x8*)(qhi + off);
            Al[mt][c] = *(const bf16x8*)(qlo + off);
        }

    float mx[2][4];
#pragma unroll
    for (int mt = 0; mt < 2; ++mt)
#pragma unroll
        for (int i = 0; i < 4; ++i) mx[mt][i] = 0.f;

    // ---------------- phase A: approximate (hi*hi) bucket maxes ----------------
#pragma unroll 2
    for (int t = 0; t < 16; ++t) {
        int at = at0 + t;
        size_t bidx = ((size_t)hbase + at) * 128 + lane;
        bf16x8 Bh0 = kh8[bidx];
        bf16x8 Bh1 = kh8[bidx + 64];
        unsigned int bw = bits2[((size_t)rt64 * N_ATAC + at * 16 + n) * 2 + word];

        f32x4 S[2];
#pragma unroll
        for (int mt = 0; mt < 2; ++mt) {
            f32x4 s = {0.f, 0.f, 0.f, 0.f};
            s = mfma16(Ah[mt][0], Bh0, s);
            s = mfma16(Ah[mt][1], Bh1, s);
            S[mt] = s;
        }
#pragma unroll
        for (int mt = 0; mt < 2; ++mt) {
            unsigned int sh = bw >> ((mt << 4) + q4);
#pragma unroll
            for (int i = 0; i < 4; ++i) {
                float v = ((sh >> i) & 1) ? S[mt][i] : 0.f;
                mx[mt][i] = fmaxf(mx[mt][i], v);
            }
        }
    }

    {
        int b = w * 16 + n;
#pragma unroll
        for (int mt = 0; mt < 2; ++mt)
#pragma unroll
            for (int i = 0; i < 4; ++i) smem[(mt * 16 + q4 + i) * 65 + b] = mx[mt][i];
    }
    __syncthreads();
    if (tid < 32) {
        int row = tid;
        float t10 = 0.f;
        for (int pass = 0; pass < 10; ++pass) {
            float best = -1.f; int bj = 0;
            for (int j = 0; j < 64; ++j) {
                float v = smem[row * 65 + j];
                if (v > best) { best = v; bj = j; }
            }
            smem[row * 65 + bj] = -1.f;
            t10 = best;
        }
        taus[row] = t10 - TAU_EPS;
    } else if (tid < 64) {
        lcnt[tid - 32] = 0;
    }
    __syncthreads();

    float tau[2][4];
#pragma unroll
    for (int mt = 0; mt < 2; ++mt)
#pragma unroll
        for (int i = 0; i < 4; ++i) tau[mt][i] = taus[mt * 16 + q4 + i];

    float* lval = smem;                 // [32][CAP]
    int*   lidx = (int*)(smem + 1024);  // [32][CAP]

    // ---------------- phase B: exact scores, collect survivors ----------------
#pragma unroll 2
    for (int t = 0; t < 16; ++t) {
        int at = at0 + t;
        size_t bidx = ((size_t)hbase + at) * 128 + lane;
        bf16x8 Bh0 = kh8[bidx];
        bf16x8 Bh1 = kh8[bidx + 64];
        bf16x8 Bl0 = kl8[bidx];
        bf16x8 Bl1 = kl8[bidx + 64];
        unsigned int bw = bits2[((size_t)rt64 * N_ATAC + at * 16 + n) * 2 + word];

        f32x4 S[2];
#pragma unroll
        for (int mt = 0; mt < 2; ++mt) {
            f32x4 s = {0.f, 0.f, 0.f, 0.f};
            s = mfma16(Ah[mt][0], Bh0, s);
            s = mfma16(Ah[mt][1], Bh1, s);
            s = mfma16(Ah[mt][0], Bl0, s);
            s = mfma16(Ah[mt][1], Bl1, s);
            s = mfma16(Al[mt][0], Bh0, s);
            s = mfma16(Al[mt][1], Bh1, s);
            S[mt] = s;
        }
        int a16 = at * 16 + n;
#pragma unroll
        for (int mt = 0; mt < 2; ++mt) {
            unsigned int sh = bw >> ((mt << 4) + q4);
#pragma unroll
            for (int i = 0; i < 4; ++i) {
                if (((sh >> i) & 1) && S[mt][i] >= tau[mt][i]) {
                    int row = mt * 16 + q4 + i;
                    int pos = atomicAdd(&lcnt[row], 1);
                    if (pos < CAP) { lval[row * CAP + pos] = S[mt][i]; lidx[row * CAP + pos] = a16; }
                }
            }
        }
    }
    __syncthreads();

    // bulk write: block exclusively owns slot ((h*4096 + r)*8 + chunk)
    if (tid < 32) {
        int c = lcnt[tid]; if (c > CAP) c = CAP;
        scnt[((size_t)h * N_RNA + r0 + tid) * NCHUNK + chunk] = c;
    }
    {
        int row = tid >> 3, j0 = tid & 7;
        int c = lcnt[row]; if (c > CAP) c = CAP;
        size_t slot = ((size_t)h * N_RNA + r0 + row) * NCHUNK + chunk;
        for (int j = j0; j < c; j += 8) {
            sval[slot * CAP + j] = lval[row * CAP + j];
            sidx[slot * CAP + j] = lidx[row * CAP + j];
        }
    }
}

// ---------------------------------------------------------------- K2: fused finalize + gather + scatter
// One wave per (h,row): wave-parallel top-10 (shuffle reduce), softmax+threshold,
// then rna_agg gather (64 cols of its head) and atac_agg atomic scatter.
__global__ __launch_bounds__(256) void fin_agg(
    const int* __restrict__ scnt, const float* __restrict__ sval, const int* __restrict__ sidx,
    const float* __restrict__ v_a, const float* __restrict__ v_r,
    float* __restrict__ rna_agg, float* __restrict__ atac_agg) {
    int wid = threadIdx.x >> 6, lane = threadIdx.x & 63;
    int p = blockIdx.x * 4 + wid;          // (h*4096 + r)
    int h = p >> 12, r = p & 4095;
    size_t sbase = (size_t)p * NCHUNK;

    // load 256 candidate slots: lane x 4
    float val[4]; int aidx[4];
#pragma unroll
    for (int j = 0; j < 4; ++j) {
        int e = j * 64 + lane;
        int chunk = e >> 5, pos = e & 31;
        int c = scnt[sbase + chunk];
        size_t sl = (sbase + chunk) * CAP + pos;
        bool ok = pos < c;
        val[j] = ok ? sval[sl] : NEG_INF;
        aidx[j] = ok ? sidx[sl] : 0;
    }

    float sv[10]; int si[10];
#pragma unroll
    for (int s = 0; s < 10; ++s) {
        float bv = val[0]; int bj = 0;
#pragma unroll
        for (int j = 1; j < 4; ++j) if (val[j] > bv) { bv = val[j]; bj = j; }
        int bmeta = (bj << 6) | lane;
#pragma unroll
        for (int off = 32; off >= 1; off >>= 1) {
            float ov = __shfl_xor(bv, off);
            int om = __shfl_xor(bmeta, off);
            if (ov > bv || (ov == bv && om < bmeta)) { bv = ov; bmeta = om; }
        }
        int wj = bmeta >> 6, wl = bmeta & 63;
        if (lane == wl) {
#pragma unroll
            for (int j = 0; j < 4; ++j) if (j == wj) val[j] = NEG_INF;
        }
        int av = aidx[0];
#pragma unroll
        for (int j = 1; j < 4; ++j) if (wj == j) av = aidx[j];
        sv[s] = bv;
        si[s] = __shfl(av, wl);
    }

    // sigmoid + softmax + threshold (same math as before)
    float wgt[10]; float sum = 0.f; float sg[10];
#pragma unroll
    for (int s = 0; s < 10; ++s) {
        sg[s] = 1.0f / (1.0f + expf(-sv[s]));
        float es = expf(sg[s]);
        wgt[s] = es;
        sum += es;
    }
    float inv = 1.0f / sum;
#pragma unroll
    for (int s = 0; s < 10; ++s) {
        wgt[s] *= inv;
        if (!(sg[s] > 0.8f)) wgt[s] = 0.f;
    }

    // rna gather: this wave owns cols [h*64, h*64+64) of row r
    float acc = 0.f;
#pragma unroll
    for (int s = 0; s < 10; ++s) {
        float vv = v_a[(size_t)si[s] * HID + h * 64 + lane];
        acc += wgt[s] * vv;
    }
    rna_agg[(size_t)r * HID + h * 64 + lane] = acc;

    // atac scatter
    float vr = v_r[(size_t)r * HID + h * 64 + lane];
#pragma unroll
    for (int s = 0; s < 10; ++s) {
        if (wgt[s] != 0.f) {
            atomicAdd(&atac_agg[(size_t)si[s] * HID + h * 64 + lane], wgt[s] * vr);
        }
    }
}

// ---------------------------------------------------------------- K3: C = A@W1 + X@W2 + bias (both outputs)
__global__ __launch_bounds__(256) void out_gemm(
    const float* __restrict__ rna_agg, const float* __restrict__ x_rna,
    const float* __restrict__ Wr1, const float* __restrict__ Wr2, const float* __restrict__ brf,
    const float* __restrict__ atac_agg, const float* __restrict__ x_atac,
    const float* __restrict__ Wa1, const float* __restrict__ Wa2, const float* __restrict__ baf,
    float* __restrict__ out_r, float* __restrict__ out_a) {
    int bx = blockIdx.x;
    const float *A, *X, *W1, *W2, *bias; float* C;
    int rb;
    if (bx < 512) { A = rna_agg; X = x_rna; W1 = Wr1; W2 = Wr2; bias = brf; C = out_r; rb = bx; }
    else { A = atac_agg; X = x_atac; W1 = Wa1; W2 = Wa2; bias = baf; C = out_a; rb = bx - 512; }
    int r = rb * 8 + (threadIdx.x >> 5);
    int cg = threadIdx.x & 31; int c0 = cg * 4;
    float4 acc = *(const float4*)&bias[c0];
    const float* a = A + (size_t)r * HID;
#pragma unroll 4
    for (int k = 0; k < 128; ++k) {
        float av = a[k];
        float4 w = *(const float4*)&W1[(size_t)k * HID + c0];
        acc.x += av * w.x; acc.y += av * w.y; acc.z += av * w.z; acc.w += av * w.w;
    }
    const float* x = X + (size_t)r * IN_C;
#pragma unroll 4
    for (int k = 0; k < 256; ++k) {
        float xv = x[k];
        float4 w = *(const float4*)&W2[(size_t)k * HID + c0];
        acc.x += xv * w.x; acc.y += xv * w.y; acc.z += xv * w.z; acc.w += xv * w.w;
    }
    *(float4*)&C[(size_t)r * HID + c0] = acc;
}

// ---------------------------------------------------------------- launch
extern "C" void kernel_launch(void* const* d_in, const int* in_sizes, int n_in,
                              void* d_out, int out_size, void* d_ws, size_t ws_size,
                              hipStream_t stream) {
    const float* x_rna = (const float*)d_in[0];
    const float* x_atac = (const float*)d_in[1];
    const float* mask = (const float*)d_in[2];
    const float* Wq = (const float*)d_in[3];  const float* bq = (const float*)d_in[4];
    const float* Wk = (const float*)d_in[5];  const float* bk = (const float*)d_in[6];
    const float* Wvr = (const float*)d_in[7]; const float* bvr = (const float*)d_in[8];
    const float* Wva = (const float*)d_in[9]; const float* bva = (const float*)d_in[10];
    const float* Wor = (const float*)d_in[11]; const float* bor = (const float*)d_in[12];
    const float* Woa = (const float*)d_in[13]; const float* boa = (const float*)d_in[14];
    const float* Wsr = (const float*)d_in[15]; const float* bsr = (const float*)d_in[16];
    const float* Wsa = (const float*)d_in[17]; const float* bsa = (const float*)d_in[18];
    const float* Wdr = (const float*)d_in[19]; const float* bdr = (const float*)d_in[20];
    const float* Wda = (const float*)d_in[21]; const float* bda = (const float*)d_in[22];

    float* out_r = (float*)d_out;
    float* out_a = out_r + N_RNA * HID;

    float* ws = (float*)d_ws;
    unsigned short* qhi = (unsigned short*)ws;            // 2*4096*64 us
    unsigned short* qlo = qhi + 524288;
    unsigned short* khf_hi = qlo + 524288;                // 2*8192*64 us (frag layout)
    unsigned short* khf_lo = khf_hi + 1048576;
    unsigned int* bits2 = (unsigned int*)(ws + 1572864);  // 64*8192*2 uint
    float* v_r = ws + 1572864 + 1048576;                  // 4096x128
    float* v_a = v_r + 524288;                            // 8192x128
    float* Wr1 = v_a + 1048576;                           // 128x128
    float* Wr2 = Wr1 + 16384;                             // 256x128
    float* brf = Wr2 + 32768;                             // 128
    float* Wa1 = brf + 128;                               // 128x128
    float* Wa2 = Wa1 + 16384;                             // 256x128
    float* baf = Wa2 + 32768;                             // 128
    int* scnt = (int*)(baf + 128);                        // 8192*8 ints
    float* sval = (float*)scnt + 65536;                   // 65536*32
    int* sidx = (int*)(sval + 2097152);                   // 65536*32
    float* rna_agg = (float*)sidx + 2097152;              // 4096x128
    float* atac_agg = rna_agg + 524288;                   // 8192x128

    hipLaunchKernelGGL(prep_all, dim3(3842), dim3(256), 0, stream,
                       mask, bits2, atac_agg,
                       Wor, bor, Woa, boa, Wsr, bsr, Wsa, bsa, Wdr, bdr, Wda, bda,
                       Wr1, Wr2, brf, Wa1, Wa2, baf,
                       x_rna, x_atac, Wq, bq, Wk, bk, Wvr, bvr, Wva, bva,
                       qhi, qlo, khf_hi, khf_lo, v_r, v_a);
    hipLaunchKernelGGL(attn2, dim3(128, 16), dim3(256), 0, stream,
                       qhi, qlo, khf_hi, khf_lo, bits2, scnt, sval, sidx);
    hipLaunchKernelGGL(fin_agg, dim3(2048), dim3(256), 0, stream,
                       scnt, sval, sidx, v_a, v_r, rna_agg, atac_agg);
    hipLaunchKernelGGL(out_gemm, dim3(1536), dim3(256), 0, stream,
                       rna_agg, x_rna, Wr1, Wr2, brf,
                       atac_agg, x_atac, Wa1, Wa2, baf, out_r, out_a);
}

// Round 7
// 444.354 us; speedup vs baseline: 1.2675x; 1.2056x over previous
//
#include <hip/hip_runtime.h>
#include <math.h>

#define N_RNA 4096
#define N_ATAC 8192
#define IN_C 256
#define HID 128
#define NH 2
#define TOPK 10
#define CAP 32
#define NCHUNK 8
#define TAU_EPS 0.12f
#define NEG_INF -3.402823466e38f

typedef __attribute__((ext_vector_type(8))) short bf16x8;
typedef __attribute__((ext_vector_type(4))) float f32x4;

static __device__ __forceinline__ f32x4 mfma16(bf16x8 a, bf16x8 b, f32x4 c) {
    return __builtin_amdgcn_mfma_f32_16x16x32_bf16(a, b, c, 0, 0, 0);
}

static __device__ __forceinline__ unsigned short f2bf(float f) {
    unsigned int u = __float_as_uint(f);
    unsigned int r = (u + 0x7fffu + ((u >> 16) & 1u)) >> 16;   // RNE
    return (unsigned short)r;
}
static __device__ __forceinline__ float bf2f(unsigned short h) {
    return __uint_as_float(((unsigned int)h) << 16);
}

// ---------------------------------------------------------------- K0: prep_all (block-ranged; long-pole projections FIRST)
// [0,384): projections.  [384,2432): mask->bits2.  [2432,3456): zero atac_agg.
// [3456,3842): fuse weights.
__global__ __launch_bounds__(256) void prep_all(
    const float* __restrict__ mask, unsigned int* __restrict__ bits2,
    float* __restrict__ atac_agg,
    const float* __restrict__ Wor, const float* __restrict__ bor,
    const float* __restrict__ Woa, const float* __restrict__ boa,
    const float* __restrict__ Wsr, const float* __restrict__ bsr,
    const float* __restrict__ Wsa, const float* __restrict__ bsa,
    const float* __restrict__ Wdr, const float* __restrict__ bdr,
    const float* __restrict__ Wda, const float* __restrict__ bda,
    float* __restrict__ Wr1, float* __restrict__ Wr2, float* __restrict__ br,
    float* __restrict__ Wa1, float* __restrict__ Wa2, float* __restrict__ ba,
    const float* __restrict__ x_rna, const float* __restrict__ x_atac,
    const float* __restrict__ Wq, const float* __restrict__ bq,
    const float* __restrict__ Wk, const float* __restrict__ bk,
    const float* __restrict__ Wvr, const float* __restrict__ bvr,
    const float* __restrict__ Wva, const float* __restrict__ bva,
    unsigned short* __restrict__ qhi, unsigned short* __restrict__ qlo,
    unsigned short* __restrict__ khf_hi, unsigned short* __restrict__ khf_lo,
    float* __restrict__ v_r, float* __restrict__ v_a) {
    __shared__ __align__(16) float x_s[64][33];
    __shared__ __align__(16) float w_s[32][128];
    int bx = blockIdx.x;
    int tid = threadIdx.x;

    if (bx >= 384 && bx < 2432) {                 // ---- mask -> bits2
        int e = bx - 384;
        int rt = e >> 5, ac = e & 31;
        int a = ac * 256 + tid;
        int r0 = rt * 64;
        unsigned int w0 = 0, w1 = 0;
#pragma unroll 8
        for (int rr = 0; rr < 32; ++rr) {
            float m0 = mask[(size_t)(r0 + rr) * N_ATAC + a];
            float m1 = mask[(size_t)(r0 + 32 + rr) * N_ATAC + a];
            w0 |= ((m0 > 0.5f) ? 1u : 0u) << rr;
            w1 |= ((m1 > 0.5f) ? 1u : 0u) << rr;
        }
        *(uint2*)&bits2[((size_t)rt * N_ATAC + a) * 2] = make_uint2(w0, w1);
        return;
    }
    if (bx >= 2432 && bx < 3456) {                // ---- zero atac_agg
        int i = (bx - 2432) * 256 + tid;
        *(float4*)&atac_agg[(size_t)i * 4] = make_float4(0.f, 0.f, 0.f, 0.f);
        return;
    }
    if (bx >= 3456) {                             // ---- fuse weights
        int f = (bx - 3456) * 256 + tid;
        if (f < 16384) {
            int i = f >> 7, j = f & 127; float s = 0.f;
            for (int t = 0; t < 128; ++t) s += Wor[i * 128 + t] * Wdr[t * 128 + j];
            Wr1[f] = s;
        } else if (f < 49152) {
            int e = f - 16384; int i = e >> 7, j = e & 127; float s = 0.f;
            for (int t = 0; t < 128; ++t) s += Wsr[i * 128 + t] * Wdr[(128 + t) * 128 + j];
            Wr2[e] = s;
        } else if (f < 65536) {
            int e = f - 49152; int i = e >> 7, j = e & 127; float s = 0.f;
            for (int t = 0; t < 128; ++t) s += Woa[i * 128 + t] * Wda[t * 128 + j];
            Wa1[e] = s;
        } else if (f < 98304) {
            int e = f - 65536; int i = e >> 7, j = e & 127; float s = 0.f;
            for (int t = 0; t < 128; ++t) s += Wsa[i * 128 + t] * Wda[(128 + t) * 128 + j];
            Wa2[e] = s;
        } else if (f < 98432) {
            int j = f - 98304; float s = bdr[j];
            for (int t = 0; t < 128; ++t) s += bor[t] * Wdr[t * 128 + j] + bsr[t] * Wdr[(128 + t) * 128 + j];
            br[j] = s;
        } else if (f < 98560) {
            int j = f - 98432; float s = bda[j];
            for (int t = 0; t < 128; ++t) s += boa[t] * Wda[t * 128 + j] + bsa[t] * Wda[(128 + t) * 128 + j];
            ba[j] = s;
        }
        return;
    }

    // ---- projections (blocks [0,384))
    int e = bx;
    int cfg, rblk;
    if (e < 64)       { cfg = 0; rblk = e; }
    else if (e < 128) { cfg = 1; rblk = e - 64; }
    else if (e < 256) { cfg = 2; rblk = e - 128; }
    else              { cfg = 3; rblk = e - 256; }
    const float *X, *W, *B;
    if (cfg == 0)      { X = x_rna;  W = Wq;  B = bq;  }
    else if (cfg == 1) { X = x_rna;  W = Wvr; B = bvr; }
    else if (cfg == 2) { X = x_atac; W = Wk;  B = bk;  }
    else               { X = x_atac; W = Wva; B = bva; }
    int r0 = rblk * 64;
    int rg = tid >> 4, cg = tid & 15;

    float acc[4][8];
#pragma unroll
    for (int i = 0; i < 4; ++i)
#pragma unroll
        for (int j = 0; j < 8; ++j) acc[i][j] = 0.f;

    for (int k0 = 0; k0 < IN_C; k0 += 32) {
        __syncthreads();
        for (int i4 = tid; i4 < 512; i4 += 256) {
            int rr = i4 >> 3, kq = i4 & 7;
            float4 v = *(const float4*)&X[(size_t)(r0 + rr) * IN_C + k0 + kq * 4];
            x_s[rr][kq * 4 + 0] = v.x; x_s[rr][kq * 4 + 1] = v.y;
            x_s[rr][kq * 4 + 2] = v.z; x_s[rr][kq * 4 + 3] = v.w;
        }
        for (int i4 = tid; i4 < 1024; i4 += 256) {
            int kk = i4 >> 5, cq = i4 & 31;
            float4 v = *(const float4*)&W[(size_t)(k0 + kk) * HID + cq * 4];
            *(float4*)&w_s[kk][cq * 4] = v;
        }
        __syncthreads();
#pragma unroll 8
        for (int kk = 0; kk < 32; ++kk) {
            float x0 = x_s[rg * 4 + 0][kk], x1 = x_s[rg * 4 + 1][kk];
            float x2 = x_s[rg * 4 + 2][kk], x3 = x_s[rg * 4 + 3][kk];
            float4 wa = *(const float4*)&w_s[kk][cg * 4];
            float4 wb = *(const float4*)&w_s[kk][64 + cg * 4];
            acc[0][0] += x0 * wa.x; acc[0][1] += x0 * wa.y; acc[0][2] += x0 * wa.z; acc[0][3] += x0 * wa.w;
            acc[0][4] += x0 * wb.x; acc[0][5] += x0 * wb.y; acc[0][6] += x0 * wb.z; acc[0][7] += x0 * wb.w;
            acc[1][0] += x1 * wa.x; acc[1][1] += x1 * wa.y; acc[1][2] += x1 * wa.z; acc[1][3] += x1 * wa.w;
            acc[1][4] += x1 * wb.x; acc[1][5] += x1 * wb.y; acc[1][6] += x1 * wb.z; acc[1][7] += x1 * wb.w;
            acc[2][0] += x2 * wa.x; acc[2][1] += x2 * wa.y; acc[2][2] += x2 * wa.z; acc[2][3] += x2 * wa.w;
            acc[2][4] += x2 * wb.x; acc[2][5] += x2 * wb.y; acc[2][6] += x2 * wb.z; acc[2][7] += x2 * wb.w;
            acc[3][0] += x3 * wa.x; acc[3][1] += x3 * wa.y; acc[3][2] += x3 * wa.z; acc[3][3] += x3 * wa.w;
            acc[3][4] += x3 * wb.x; acc[3][5] += x3 * wb.y; acc[3][6] += x3 * wb.z; acc[3][7] += x3 * wb.w;
        }
    }
    float bv[8];
#pragma unroll
    for (int j = 0; j < 8; ++j) {
        int c = (j < 4) ? (cg * 4 + j) : (64 + cg * 4 + (j - 4));
        bv[j] = B[c];
    }
    if (cfg == 0 || cfg == 2) {
#pragma unroll
        for (int i = 0; i < 4; ++i) {
            int r = r0 + rg * 4 + i;
            float va[8];
#pragma unroll
            for (int j = 0; j < 8; ++j) va[j] = acc[i][j] + bv[j];
            ushort4 h0, l0, h1, l1;
            h0.x = f2bf(va[0]); h0.y = f2bf(va[1]); h0.z = f2bf(va[2]); h0.w = f2bf(va[3]);
            h1.x = f2bf(va[4]); h1.y = f2bf(va[5]); h1.z = f2bf(va[6]); h1.w = f2bf(va[7]);
            l0.x = f2bf(va[0] - bf2f(h0.x)); l0.y = f2bf(va[1] - bf2f(h0.y));
            l0.z = f2bf(va[2] - bf2f(h0.z)); l0.w = f2bf(va[3] - bf2f(h0.w));
            l1.x = f2bf(va[4] - bf2f(h1.x)); l1.y = f2bf(va[5] - bf2f(h1.y));
            l1.z = f2bf(va[6] - bf2f(h1.z)); l1.w = f2bf(va[7] - bf2f(h1.w));
            if (cfg == 0) {
                size_t o0 = (size_t)r * 64 + cg * 4;
                size_t o1 = (size_t)(N_RNA + r) * 64 + cg * 4;
                *(ushort4*)&qhi[o0] = h0; *(ushort4*)&qhi[o1] = h1;
                *(ushort4*)&qlo[o0] = l0; *(ushort4*)&qlo[o1] = l1;
            } else {
                int at = r >> 4, n = r & 15;
                int kc = cg >> 1, ee = (cg & 1) * 4;
                size_t o0 = ((size_t)(at) * 8 + kc) * 128 + n * 8 + ee;
                size_t o1 = ((size_t)(512 + at) * 8 + kc) * 128 + n * 8 + ee;
                *(ushort4*)&khf_hi[o0] = h0; *(ushort4*)&khf_hi[o1] = h1;
                *(ushort4*)&khf_lo[o0] = l0; *(ushort4*)&khf_lo[o1] = l1;
            }
        }
    } else {
        float* C = (cfg == 1) ? v_r : v_a;
#pragma unroll
        for (int i = 0; i < 4; ++i) {
            int r = r0 + rg * 4 + i;
            float4 oa = make_float4(acc[i][0] + bv[0], acc[i][1] + bv[1], acc[i][2] + bv[2], acc[i][3] + bv[3]);
            float4 ob = make_float4(acc[i][4] + bv[4], acc[i][5] + bv[5], acc[i][6] + bv[6], acc[i][7] + bv[7]);
            *(float4*)&C[(size_t)r * HID + cg * 4] = oa;
            *(float4*)&C[(size_t)r * HID + 64 + cg * 4] = ob;
        }
    }
}

// ---------------------------------------------------------------- K1: two-phase MFMA attention (XCD-pinned by hq)
// grid (16 = h*8+chunk, 64 rtiles of 64 rows).  blockIdx.x fastest -> linear%8
// pins each a-chunk's K-slice + bits slice to one XCD (L2-resident); q streams via L3.
// Phase A: approx (hi*hi) bucket maxes -> tau = 10th bucket max - slack.
// Phase B: exact 3-pass, survivors -> LDS lists (reusing bmax storage).
__global__ __launch_bounds__(256, 4) void attn2(
    const unsigned short* __restrict__ qhi, const unsigned short* __restrict__ qlo,
    const unsigned short* __restrict__ khf_hi, const unsigned short* __restrict__ khf_lo,
    const unsigned int* __restrict__ bits2,
    int* __restrict__ scnt, float* __restrict__ sval, int* __restrict__ sidx) {
    int hq = blockIdx.x; int h = hq >> 3, chunk = hq & 7;
    int rt = blockIdx.y; int r0 = rt * 64;
    int tid = threadIdx.x;
    int w = tid >> 6, lane = tid & 63;
    int n = lane & 15, quad = lane >> 4;
    int q4 = quad * 4;
    int at0 = chunk * 64 + w * 16;          // a-tile base (16 a per tile)
    int hbase = h * 512;

    __shared__ __align__(16) float smem[64 * 65];   // bmax [64][65]; reused: lval[64][32] | lidx[64][32]
    __shared__ float taus[64];
    __shared__ int   lcnt[64];

    const bf16x8* kh8 = (const bf16x8*)khf_hi;
    const bf16x8* kl8 = (const bf16x8*)khf_lo;
    const uint2* b2 = (const uint2*)bits2;

    // Preload A-frags: 4 m-tiles x 2 k-chunks, hi+lo
    bf16x8 Ah[4][2], Al[4][2];
#pragma unroll
    for (int mt = 0; mt < 4; ++mt)
#pragma unroll
        for (int c = 0; c < 2; ++c) {
            size_t off = ((size_t)h * N_RNA + r0 + mt * 16 + n) * 64 + c * 32 + quad * 8;
            Ah[mt][c] = *(const bf16x8*)(qhi + off);
            Al[mt][c] = *(const bf16x8*)(qlo + off);
        }

    float mx[4][4];
#pragma unroll
    for (int mt = 0; mt < 4; ++mt)
#pragma unroll
        for (int i = 0; i < 4; ++i) mx[mt][i] = 0.f;

    // ---------------- phase A: approximate (hi*hi) bucket maxes ----------------
#pragma unroll 2
    for (int t = 0; t < 16; ++t) {
        int at = at0 + t;
        size_t bidx = ((size_t)hbase + at) * 128 + lane;
        bf16x8 Bh0 = kh8[bidx];
        bf16x8 Bh1 = kh8[bidx + 64];
        uint2 bl = b2[(size_t)rt * N_ATAC + at * 16 + n];

        f32x4 S[4];
#pragma unroll
        for (int mt = 0; mt < 4; ++mt) {
            f32x4 s = {0.f, 0.f, 0.f, 0.f};
            s = mfma16(Ah[mt][0], Bh0, s);
            s = mfma16(Ah[mt][1], Bh1, s);
            S[mt] = s;
        }
#pragma unroll
        for (int mt = 0; mt < 4; ++mt) {
            unsigned int bw = (mt < 2) ? bl.x : bl.y;
            unsigned int sh = bw >> (((mt & 1) << 4) + q4);
#pragma unroll
            for (int i = 0; i < 4; ++i) {
                float v = ((sh >> i) & 1) ? S[mt][i] : 0.f;
                mx[mt][i] = fmaxf(mx[mt][i], v);
            }
        }
    }

    {
        int b = w * 16 + n;
#pragma unroll
        for (int mt = 0; mt < 4; ++mt)
#pragma unroll
            for (int i = 0; i < 4; ++i) smem[(mt * 16 + q4 + i) * 65 + b] = mx[mt][i];
    }
    __syncthreads();
    if (tid < 64) {
        int row = tid;
        float t10 = 0.f;
        for (int pass = 0; pass < 10; ++pass) {
            float best = -1.f; int bj = 0;
            for (int j = 0; j < 64; ++j) {
                float v = smem[row * 65 + j];
                if (v > best) { best = v; bj = j; }
            }
            smem[row * 65 + bj] = -1.f;
            t10 = best;
        }
        taus[row] = t10 - TAU_EPS;
    } else if (tid < 128) {
        lcnt[tid - 64] = 0;
    }
    __syncthreads();

    float tau[4][4];
#pragma unroll
    for (int mt = 0; mt < 4; ++mt)
#pragma unroll
        for (int i = 0; i < 4; ++i) tau[mt][i] = taus[mt * 16 + q4 + i];

    float* lval = smem;                 // [64][CAP]
    int*   lidx = (int*)(smem + 2048);  // [64][CAP]

    // ---------------- phase B: exact scores, collect survivors ----------------
#pragma unroll 2
    for (int t = 0; t < 16; ++t) {
        int at = at0 + t;
        size_t bidx = ((size_t)hbase + at) * 128 + lane;
        bf16x8 Bh0 = kh8[bidx];
        bf16x8 Bh1 = kh8[bidx + 64];
        bf16x8 Bl0 = kl8[bidx];
        bf16x8 Bl1 = kl8[bidx + 64];
        uint2 bl = b2[(size_t)rt * N_ATAC + at * 16 + n];

        f32x4 S[4];
#pragma unroll
        for (int mt = 0; mt < 4; ++mt) {
            f32x4 s = {0.f, 0.f, 0.f, 0.f};
            s = mfma16(Ah[mt][0], Bh0, s);
            s = mfma16(Ah[mt][1], Bh1, s);
            s = mfma16(Ah[mt][0], Bl0, s);
            s = mfma16(Ah[mt][1], Bl1, s);
            s = mfma16(Al[mt][0], Bh0, s);
            s = mfma16(Al[mt][1], Bh1, s);
            S[mt] = s;
        }
        int a16 = at * 16 + n;
#pragma unroll
        for (int mt = 0; mt < 4; ++mt) {
            unsigned int bw = (mt < 2) ? bl.x : bl.y;
            unsigned int sh = bw >> (((mt & 1) << 4) + q4);
#pragma unroll
            for (int i = 0; i < 4; ++i) {
                if (((sh >> i) & 1) && S[mt][i] >= tau[mt][i]) {
                    int row = mt * 16 + q4 + i;
                    int pos = atomicAdd(&lcnt[row], 1);
                    if (pos < CAP) { lval[row * CAP + pos] = S[mt][i]; lidx[row * CAP + pos] = a16; }
                }
            }
        }
    }
    __syncthreads();

    // bulk write: block exclusively owns slot ((h*4096 + r)*8 + chunk)
    if (tid < 64) {
        int c = lcnt[tid]; if (c > CAP) c = CAP;
        scnt[((size_t)h * N_RNA + r0 + tid) * NCHUNK + chunk] = c;
    }
    {
        int row = tid >> 2, j0 = tid & 3;
        int c = lcnt[row]; if (c > CAP) c = CAP;
        size_t slot = ((size_t)h * N_RNA + r0 + row) * NCHUNK + chunk;
        for (int j = j0; j < c; j += 4) {
            sval[slot * CAP + j] = lval[row * CAP + j];
            sidx[slot * CAP + j] = lidx[row * CAP + j];
        }
    }
}

// ---------------------------------------------------------------- K2: fused finalize + gather + scatter
__global__ __launch_bounds__(256) void fin_agg(
    const int* __restrict__ scnt, const float* __restrict__ sval, const int* __restrict__ sidx,
    const float* __restrict__ v_a, const float* __restrict__ v_r,
    float* __restrict__ rna_agg, float* __restrict__ atac_agg) {
    int wid = threadIdx.x >> 6, lane = threadIdx.x & 63;
    int p = blockIdx.x * 4 + wid;          // (h*4096 + r)
    int h = p >> 12, r = p & 4095;
    size_t sbase = (size_t)p * NCHUNK;

    float val[4]; int aidx[4];
#pragma unroll
    for (int j = 0; j < 4; ++j) {
        int e = j * 64 + lane;
        int chunk = e >> 5, pos = e & 31;
        int c = scnt[sbase + chunk];
        size_t sl = (sbase + chunk) * CAP + pos;
        bool ok = pos < c;
        val[j] = ok ? sval[sl] : NEG_INF;
        aidx[j] = ok ? sidx[sl] : 0;
    }

    float sv[10]; int si[10];
#pragma unroll
    for (int s = 0; s < 10; ++s) {
        float bv = val[0]; int bj = 0;
#pragma unroll
        for (int j = 1; j < 4; ++j) if (val[j] > bv) { bv = val[j]; bj = j; }
        int bmeta = (bj << 6) | lane;
#pragma unroll
        for (int off = 32; off >= 1; off >>= 1) {
            float ov = __shfl_xor(bv, off);
            int om = __shfl_xor(bmeta, off);
            if (ov > bv || (ov == bv && om < bmeta)) { bv = ov; bmeta = om; }
        }
        int wj = bmeta >> 6, wl = bmeta & 63;
        if (lane == wl) {
#pragma unroll
            for (int j = 0; j < 4; ++j) if (j == wj) val[j] = NEG_INF;
        }
        int av = aidx[0];
#pragma unroll
        for (int j = 1; j < 4; ++j) if (wj == j) av = aidx[j];
        sv[s] = bv;
        si[s] = __shfl(av, wl);
    }

    float wgt[10]; float sum = 0.f; float sg[10];
#pragma unroll
    for (int s = 0; s < 10; ++s) {
        sg[s] = 1.0f / (1.0f + expf(-sv[s]));
        float es = expf(sg[s]);
        wgt[s] = es;
        sum += es;
    }
    float inv = 1.0f / sum;
#pragma unroll
    for (int s = 0; s < 10; ++s) {
        wgt[s] *= inv;
        if (!(sg[s] > 0.8f)) wgt[s] = 0.f;
    }

    float acc = 0.f;
#pragma unroll
    for (int s = 0; s < 10; ++s) {
        float vv = v_a[(size_t)si[s] * HID + h * 64 + lane];
        acc += wgt[s] * vv;
    }
    rna_agg[(size_t)r * HID + h * 64 + lane] = acc;

    float vr = v_r[(size_t)r * HID + h * 64 + lane];
#pragma unroll
    for (int s = 0; s < 10; ++s) {
        if (wgt[s] != 0.f) {
            atomicAdd(&atac_agg[(size_t)si[s] * HID + h * 64 + lane], wgt[s] * vr);
        }
    }
}

// ---------------------------------------------------------------- K3: out = [Agg|X] @ [W1;W2] + bias, LDS-tiled
// grid 384: tiles of 32 rows.  [0,128): rna rows; [128,384): atac rows.
__global__ __launch_bounds__(256) void out_gemm(
    const float* __restrict__ rna_agg, const float* __restrict__ x_rna,
    const float* __restrict__ Wr1, const float* __restrict__ Wr2, const float* __restrict__ brf,
    const float* __restrict__ atac_agg, const float* __restrict__ x_atac,
    const float* __restrict__ Wa1, const float* __restrict__ Wa2, const float* __restrict__ baf,
    float* __restrict__ out_r, float* __restrict__ out_a) {
    __shared__ __align__(16) float x_s[32][33];
    __shared__ __align__(16) float w_s[32][128];
    int bx = blockIdx.x;
    const float *A, *X, *W1, *W2, *bias; float* C;
    int r0;
    if (bx < 128) { A = rna_agg; X = x_rna; W1 = Wr1; W2 = Wr2; bias = brf; C = out_r; r0 = bx * 32; }
    else { A = atac_agg; X = x_atac; W1 = Wa1; W2 = Wa2; bias = baf; C = out_a; r0 = (bx - 128) * 32; }
    int tid = threadIdx.x;
    int rg = tid >> 4, cg = tid & 15;

    float acc[2][8];
#pragma unroll
    for (int i = 0; i < 2; ++i)
#pragma unroll
        for (int j = 0; j < 8; ++j) acc[i][j] = 0.f;

    for (int k0 = 0; k0 < 384; k0 += 32) {
        __syncthreads();
        {   // stage 32 rows x 32 k of [A|X]
            int rr = tid >> 3, kq = tid & 7;
            float4 v;
            if (k0 < 128) v = *(const float4*)&A[(size_t)(r0 + rr) * HID + k0 + kq * 4];
            else          v = *(const float4*)&X[(size_t)(r0 + rr) * IN_C + (k0 - 128) + kq * 4];
            x_s[rr][kq * 4 + 0] = v.x; x_s[rr][kq * 4 + 1] = v.y;
            x_s[rr][kq * 4 + 2] = v.z; x_s[rr][kq * 4 + 3] = v.w;
        }
        for (int i4 = tid; i4 < 1024; i4 += 256) {   // stage 32 k x 128 cols of [W1;W2]
            int kk = i4 >> 5, cq = i4 & 31;
            float4 v;
            if (k0 < 128) v = *(const float4*)&W1[(size_t)(k0 + kk) * HID + cq * 4];
            else          v = *(const float4*)&W2[(size_t)(k0 - 128 + kk) * HID + cq * 4];
            *(float4*)&w_s[kk][cq * 4] = v;
        }
        __syncthreads();
#pragma unroll 8
        for (int kk = 0; kk < 32; ++kk) {
            float x0 = x_s[rg * 2 + 0][kk], x1 = x_s[rg * 2 + 1][kk];
            float4 wa = *(const float4*)&w_s[kk][cg * 4];
            float4 wb = *(const float4*)&w_s[kk][64 + cg * 4];
            acc[0][0] += x0 * wa.x; acc[0][1] += x0 * wa.y; acc[0][2] += x0 * wa.z; acc[0][3] += x0 * wa.w;
            acc[0][4] += x0 * wb.x; acc[0][5] += x0 * wb.y; acc[0][6] += x0 * wb.z; acc[0][7] += x0 * wb.w;
            acc[1][0] += x1 * wa.x; acc[1][1] += x1 * wa.y; acc[1][2] += x1 * wa.z; acc[1][3] += x1 * wa.w;
            acc[1][4] += x1 * wb.x; acc[1][5] += x1 * wb.y; acc[1][6] += x1 * wb.z; acc[1][7] += x1 * wb.w;
        }
    }
    float bv[8];
#pragma unroll
    for (int j = 0; j < 8; ++j) {
        int c = (j < 4) ? (cg * 4 + j) : (64 + cg * 4 + (j - 4));
        bv[j] = bias[c];
    }
#pragma unroll
    for (int i = 0; i < 2; ++i) {
        int r = r0 + rg * 2 + i;
        float4 oa = make_float4(acc[i][0] + bv[0], acc[i][1] + bv[1], acc[i][2] + bv[2], acc[i][3] + bv[3]);
        float4 ob = make_float4(acc[i][4] + bv[4], acc[i][5] + bv[5], acc[i][6] + bv[6], acc[i][7] + bv[7]);
        *(float4*)&C[(size_t)r * HID + cg * 4] = oa;
        *(float4*)&C[(size_t)r * HID + 64 + cg * 4] = ob;
    }
}

// ---------------------------------------------------------------- launch
extern "C" void kernel_launch(void* const* d_in, const int* in_sizes, int n_in,
                              void* d_out, int out_size, void* d_ws, size_t ws_size,
                              hipStream_t stream) {
    const float* x_rna = (const float*)d_in[0];
    const float* x_atac = (const float*)d_in[1];
    const float* mask = (const float*)d_in[2];
    const float* Wq = (const float*)d_in[3];  const float* bq = (const float*)d_in[4];
    const float* Wk = (const float*)d_in[5];  const float* bk = (const float*)d_in[6];
    const float* Wvr = (const float*)d_in[7]; const float* bvr = (const float*)d_in[8];
    const float* Wva = (const float*)d_in[9]; const float* bva = (const float*)d_in[10];
    const float* Wor = (const float*)d_in[11]; const float* bor = (const float*)d_in[12];
    const float* Woa = (const float*)d_in[13]; const float* boa = (const float*)d_in[14];
    const float* Wsr = (const float*)d_in[15]; const float* bsr = (const float*)d_in[16];
    const float* Wsa = (const float*)d_in[17]; const float* bsa = (const float*)d_in[18];
    const float* Wdr = (const float*)d_in[19]; const float* bdr = (const float*)d_in[20];
    const float* Wda = (const float*)d_in[21]; const float* bda = (const float*)d_in[22];

    float* out_r = (float*)d_out;
    float* out_a = out_r + N_RNA * HID;

    float* ws = (float*)d_ws;
    unsigned short* qhi = (unsigned short*)ws;            // 2*4096*64 us
    unsigned short* qlo = qhi + 524288;
    unsigned short* khf_hi = qlo + 524288;                // 2*8192*64 us (frag layout)
    unsigned short* khf_lo = khf_hi + 1048576;
    unsigned int* bits2 = (unsigned int*)(ws + 1572864);  // 64*8192*2 uint
    float* v_r = ws + 1572864 + 1048576;                  // 4096x128
    float* v_a = v_r + 524288;                            // 8192x128
    float* Wr1 = v_a + 1048576;                           // 128x128
    float* Wr2 = Wr1 + 16384;                             // 256x128
    float* brf = Wr2 + 32768;                             // 128
    float* Wa1 = brf + 128;                               // 128x128
    float* Wa2 = Wa1 + 16384;                             // 256x128
    float* baf = Wa2 + 32768;                             // 128
    int* scnt = (int*)(baf + 128);                        // 8192*8 ints
    float* sval = (float*)scnt + 65536;                   // 65536*32
    int* sidx = (int*)(sval + 2097152);                   // 65536*32
    float* rna_agg = (float*)sidx + 2097152;              // 4096x128
    float* atac_agg = rna_agg + 524288;                   // 8192x128

    hipLaunchKernelGGL(prep_all, dim3(3842), dim3(256), 0, stream,
                       mask, bits2, atac_agg,
                       Wor, bor, Woa, boa, Wsr, bsr, Wsa, bsa, Wdr, bdr, Wda, bda,
                       Wr1, Wr2, brf, Wa1, Wa2, baf,
                       x_rna, x_atac, Wq, bq, Wk, bk, Wvr, bvr, Wva, bva,
                       qhi, qlo, khf_hi, khf_lo, v_r, v_a);
    hipLaunchKernelGGL(attn2, dim3(16, 64), dim3(256), 0, stream,
                       qhi, qlo, khf_hi, khf_lo, bits2, scnt, sval, sidx);
    hipLaunchKernelGGL(fin_agg, dim3(2048), dim3(256), 0, stream,
                       scnt, sval, sidx, v_a, v_r, rna_agg, atac_agg);
    hipLaunchKernelGGL(out_gemm, dim3(384), dim3(256), 0, stream,
                       rna_agg, x_rna, Wr1, Wr2, brf,
                       atac_agg, x_atac, Wa1, Wa2, baf, out_r, out_a);
}

// Round 8
// 425.115 us; speedup vs baseline: 1.3248x; 1.0453x over previous
//
#include <hip/hip_runtime.h>
#include <math.h>

#define N_RNA 4096
#define N_ATAC 8192
#define IN_C 256
#define HID 128
#define NH 2
#define TOPK 10
#define CAP 32
#define NCHUNK 8
#define TAU_EPS 0.12f
#define NEG_INF -3.402823466e38f

typedef __attribute__((ext_vector_type(8))) short bf16x8;
typedef __attribute__((ext_vector_type(4))) float f32x4;

static __device__ __forceinline__ f32x4 mfma16(bf16x8 a, bf16x8 b, f32x4 c) {
    return __builtin_amdgcn_mfma_f32_16x16x32_bf16(a, b, c, 0, 0, 0);
}

static __device__ __forceinline__ unsigned short f2bf(float f) {
    unsigned int u = __float_as_uint(f);
    unsigned int r = (u + 0x7fffu + ((u >> 16) & 1u)) >> 16;   // RNE
    return (unsigned short)r;
}
static __device__ __forceinline__ float bf2f(unsigned short h) {
    return __uint_as_float(((unsigned int)h) << 16);
}

// ---------------------------------------------------------------- K0: prep_all (block-ranged; projections FIRST)
// [0,384): projections.  [384,896): mask->bits2 (float4).  [896,1152): zero atac_agg.
// [1152,1538): fuse weights.
__global__ __launch_bounds__(256) void prep_all(
    const float* __restrict__ mask, unsigned int* __restrict__ bits2,
    float* __restrict__ atac_agg,
    const float* __restrict__ Wor, const float* __restrict__ bor,
    const float* __restrict__ Woa, const float* __restrict__ boa,
    const float* __restrict__ Wsr, const float* __restrict__ bsr,
    const float* __restrict__ Wsa, const float* __restrict__ bsa,
    const float* __restrict__ Wdr, const float* __restrict__ bdr,
    const float* __restrict__ Wda, const float* __restrict__ bda,
    float* __restrict__ Wr1, float* __restrict__ Wr2, float* __restrict__ br,
    float* __restrict__ Wa1, float* __restrict__ Wa2, float* __restrict__ ba,
    const float* __restrict__ x_rna, const float* __restrict__ x_atac,
    const float* __restrict__ Wq, const float* __restrict__ bq,
    const float* __restrict__ Wk, const float* __restrict__ bk,
    const float* __restrict__ Wvr, const float* __restrict__ bvr,
    const float* __restrict__ Wva, const float* __restrict__ bva,
    unsigned short* __restrict__ qhi, unsigned short* __restrict__ qlo,
    unsigned short* __restrict__ khf_hi, unsigned short* __restrict__ khf_lo,
    float* __restrict__ v_r, float* __restrict__ v_a) {
    __shared__ __align__(16) float x_s[64][33];
    __shared__ __align__(16) float w_s[32][128];
    int bx = blockIdx.x;
    int tid = threadIdx.x;

    if (bx >= 384 && bx < 896) {                  // ---- mask -> bits2, float4 (4 a/thread)
        int e = bx - 384;
        int rt = e >> 3, ac = e & 7;
        int a0 = ac * 1024 + tid * 4;
        int r0 = rt * 64;
        unsigned int w0[4] = {0, 0, 0, 0}, w1[4] = {0, 0, 0, 0};
#pragma unroll 8
        for (int rr = 0; rr < 32; ++rr) {
            float4 m0 = *(const float4*)&mask[(size_t)(r0 + rr) * N_ATAC + a0];
            float4 m1 = *(const float4*)&mask[(size_t)(r0 + 32 + rr) * N_ATAC + a0];
            w0[0] |= ((m0.x > 0.5f) ? 1u : 0u) << rr;
            w0[1] |= ((m0.y > 0.5f) ? 1u : 0u) << rr;
            w0[2] |= ((m0.z > 0.5f) ? 1u : 0u) << rr;
            w0[3] |= ((m0.w > 0.5f) ? 1u : 0u) << rr;
            w1[0] |= ((m1.x > 0.5f) ? 1u : 0u) << rr;
            w1[1] |= ((m1.y > 0.5f) ? 1u : 0u) << rr;
            w1[2] |= ((m1.z > 0.5f) ? 1u : 0u) << rr;
            w1[3] |= ((m1.w > 0.5f) ? 1u : 0u) << rr;
        }
        unsigned int* dst = &bits2[((size_t)rt * N_ATAC + a0) * 2];
        uint4 o0 = make_uint4(w0[0], w1[0], w0[1], w1[1]);
        uint4 o1 = make_uint4(w0[2], w1[2], w0[3], w1[3]);
        *(uint4*)&dst[0] = o0;
        *(uint4*)&dst[4] = o1;
        return;
    }
    if (bx >= 896 && bx < 1152) {                 // ---- zero atac_agg (64 B/thread)
        size_t i = ((size_t)(bx - 896) * 256 + tid) * 16;
        float4 z = make_float4(0.f, 0.f, 0.f, 0.f);
        *(float4*)&atac_agg[i] = z;
        *(float4*)&atac_agg[i + 4] = z;
        *(float4*)&atac_agg[i + 8] = z;
        *(float4*)&atac_agg[i + 12] = z;
        return;
    }
    if (bx >= 1152) {                             // ---- fuse weights
        int f = (bx - 1152) * 256 + tid;
        if (f < 16384) {
            int i = f >> 7, j = f & 127; float s = 0.f;
            for (int t = 0; t < 128; ++t) s += Wor[i * 128 + t] * Wdr[t * 128 + j];
            Wr1[f] = s;
        } else if (f < 49152) {
            int e = f - 16384; int i = e >> 7, j = e & 127; float s = 0.f;
            for (int t = 0; t < 128; ++t) s += Wsr[i * 128 + t] * Wdr[(128 + t) * 128 + j];
            Wr2[e] = s;
        } else if (f < 65536) {
            int e = f - 49152; int i = e >> 7, j = e & 127; float s = 0.f;
            for (int t = 0; t < 128; ++t) s += Woa[i * 128 + t] * Wda[t * 128 + j];
            Wa1[e] = s;
        } else if (f < 98304) {
            int e = f - 65536; int i = e >> 7, j = e & 127; float s = 0.f;
            for (int t = 0; t < 128; ++t) s += Wsa[i * 128 + t] * Wda[(128 + t) * 128 + j];
            Wa2[e] = s;
        } else if (f < 98432) {
            int j = f - 98304; float s = bdr[j];
            for (int t = 0; t < 128; ++t) s += bor[t] * Wdr[t * 128 + j] + bsr[t] * Wdr[(128 + t) * 128 + j];
            br[j] = s;
        } else if (f < 98560) {
            int j = f - 98432; float s = bda[j];
            for (int t = 0; t < 128; ++t) s += boa[t] * Wda[t * 128 + j] + bsa[t] * Wda[(128 + t) * 128 + j];
            ba[j] = s;
        }
        return;
    }

    // ---- projections (blocks [0,384))
    int e = bx;
    int cfg, rblk;
    if (e < 64)       { cfg = 0; rblk = e; }
    else if (e < 128) { cfg = 1; rblk = e - 64; }
    else if (e < 256) { cfg = 2; rblk = e - 128; }
    else              { cfg = 3; rblk = e - 256; }
    const float *X, *W, *B;
    if (cfg == 0)      { X = x_rna;  W = Wq;  B = bq;  }
    else if (cfg == 1) { X = x_rna;  W = Wvr; B = bvr; }
    else if (cfg == 2) { X = x_atac; W = Wk;  B = bk;  }
    else               { X = x_atac; W = Wva; B = bva; }
    int r0 = rblk * 64;
    int rg = tid >> 4, cg = tid & 15;

    float acc[4][8];
#pragma unroll
    for (int i = 0; i < 4; ++i)
#pragma unroll
        for (int j = 0; j < 8; ++j) acc[i][j] = 0.f;

    for (int k0 = 0; k0 < IN_C; k0 += 32) {
        __syncthreads();
        for (int i4 = tid; i4 < 512; i4 += 256) {
            int rr = i4 >> 3, kq = i4 & 7;
            float4 v = *(const float4*)&X[(size_t)(r0 + rr) * IN_C + k0 + kq * 4];
            x_s[rr][kq * 4 + 0] = v.x; x_s[rr][kq * 4 + 1] = v.y;
            x_s[rr][kq * 4 + 2] = v.z; x_s[rr][kq * 4 + 3] = v.w;
        }
        for (int i4 = tid; i4 < 1024; i4 += 256) {
            int kk = i4 >> 5, cq = i4 & 31;
            float4 v = *(const float4*)&W[(size_t)(k0 + kk) * HID + cq * 4];
            *(float4*)&w_s[kk][cq * 4] = v;
        }
        __syncthreads();
#pragma unroll 8
        for (int kk = 0; kk < 32; ++kk) {
            float x0 = x_s[rg * 4 + 0][kk], x1 = x_s[rg * 4 + 1][kk];
            float x2 = x_s[rg * 4 + 2][kk], x3 = x_s[rg * 4 + 3][kk];
            float4 wa = *(const float4*)&w_s[kk][cg * 4];
            float4 wb = *(const float4*)&w_s[kk][64 + cg * 4];
            acc[0][0] += x0 * wa.x; acc[0][1] += x0 * wa.y; acc[0][2] += x0 * wa.z; acc[0][3] += x0 * wa.w;
            acc[0][4] += x0 * wb.x; acc[0][5] += x0 * wb.y; acc[0][6] += x0 * wb.z; acc[0][7] += x0 * wb.w;
            acc[1][0] += x1 * wa.x; acc[1][1] += x1 * wa.y; acc[1][2] += x1 * wa.z; acc[1][3] += x1 * wa.w;
            acc[1][4] += x1 * wb.x; acc[1][5] += x1 * wb.y; acc[1][6] += x1 * wb.z; acc[1][7] += x1 * wb.w;
            acc[2][0] += x2 * wa.x; acc[2][1] += x2 * wa.y; acc[2][2] += x2 * wa.z; acc[2][3] += x2 * wa.w;
            acc[2][4] += x2 * wb.x; acc[2][5] += x2 * wb.y; acc[2][6] += x2 * wb.z; acc[2][7] += x2 * wb.w;
            acc[3][0] += x3 * wa.x; acc[3][1] += x3 * wa.y; acc[3][2] += x3 * wa.z; acc[3][3] += x3 * wa.w;
            acc[3][4] += x3 * wb.x; acc[3][5] += x3 * wb.y; acc[3][6] += x3 * wb.z; acc[3][7] += x3 * wb.w;
        }
    }
    float bv[8];
#pragma unroll
    for (int j = 0; j < 8; ++j) {
        int c = (j < 4) ? (cg * 4 + j) : (64 + cg * 4 + (j - 4));
        bv[j] = B[c];
    }
    if (cfg == 0 || cfg == 2) {
#pragma unroll
        for (int i = 0; i < 4; ++i) {
            int r = r0 + rg * 4 + i;
            float va[8];
#pragma unroll
            for (int j = 0; j < 8; ++j) va[j] = acc[i][j] + bv[j];
            ushort4 h0, l0, h1, l1;
            h0.x = f2bf(va[0]); h0.y = f2bf(va[1]); h0.z = f2bf(va[2]); h0.w = f2bf(va[3]);
            h1.x = f2bf(va[4]); h1.y = f2bf(va[5]); h1.z = f2bf(va[6]); h1.w = f2bf(va[7]);
            l0.x = f2bf(va[0] - bf2f(h0.x)); l0.y = f2bf(va[1] - bf2f(h0.y));
            l0.z = f2bf(va[2] - bf2f(h0.z)); l0.w = f2bf(va[3] - bf2f(h0.w));
            l1.x = f2bf(va[4] - bf2f(h1.x)); l1.y = f2bf(va[5] - bf2f(h1.y));
            l1.z = f2bf(va[6] - bf2f(h1.z)); l1.w = f2bf(va[7] - bf2f(h1.w));
            if (cfg == 0) {
                size_t o0 = (size_t)r * 64 + cg * 4;
                size_t o1 = (size_t)(N_RNA + r) * 64 + cg * 4;
                *(ushort4*)&qhi[o0] = h0; *(ushort4*)&qhi[o1] = h1;
                *(ushort4*)&qlo[o0] = l0; *(ushort4*)&qlo[o1] = l1;
            } else {
                int at = r >> 4, n = r & 15;
                int kc = cg >> 1, ee = (cg & 1) * 4;
                size_t o0 = ((size_t)(at) * 8 + kc) * 128 + n * 8 + ee;
                size_t o1 = ((size_t)(512 + at) * 8 + kc) * 128 + n * 8 + ee;
                *(ushort4*)&khf_hi[o0] = h0; *(ushort4*)&khf_hi[o1] = h1;
                *(ushort4*)&khf_lo[o0] = l0; *(ushort4*)&khf_lo[o1] = l1;
            }
        }
    } else {
        float* C = (cfg == 1) ? v_r : v_a;
#pragma unroll
        for (int i = 0; i < 4; ++i) {
            int r = r0 + rg * 4 + i;
            float4 oa = make_float4(acc[i][0] + bv[0], acc[i][1] + bv[1], acc[i][2] + bv[2], acc[i][3] + bv[3]);
            float4 ob = make_float4(acc[i][4] + bv[4], acc[i][5] + bv[5], acc[i][6] + bv[6], acc[i][7] + bv[7]);
            *(float4*)&C[(size_t)r * HID + cg * 4] = oa;
            *(float4*)&C[(size_t)r * HID + 64 + cg * 4] = ob;
        }
    }
}

// ---------------------------------------------------------------- K1: two-phase MFMA attention
// grid (16 = h*8+chunk, 128 rtiles of 32 rows), block 256 (4 waves).
// blockIdx.x fastest -> linear%8 = chunk pins each a-chunk's K+bits slice (~1 MB)
// to one XCD L2; q streams via L3.  32-row body fits 64 VGPR (no spill, per R5).
__global__ __launch_bounds__(256, 4) void attn2(
    const unsigned short* __restrict__ qhi, const unsigned short* __restrict__ qlo,
    const unsigned short* __restrict__ khf_hi, const unsigned short* __restrict__ khf_lo,
    const unsigned int* __restrict__ bits2,
    int* __restrict__ scnt, float* __restrict__ sval, int* __restrict__ sidx) {
    int hq = blockIdx.x; int h = hq >> 3, chunk = hq & 7;
    int rt = blockIdx.y; int r0 = rt * 32;
    int tid = threadIdx.x;
    int w = tid >> 6, lane = tid & 63;
    int n = lane & 15, quad = lane >> 4;
    int q4 = quad * 4;
    int at0 = chunk * 64 + w * 16;          // a-tile base (16 a per tile)
    int hbase = h * 512;
    int rt64 = rt >> 1, word = rt & 1;

    __shared__ __align__(16) float smem[32 * 65];   // bmax [32][65]; reused: lval[32][32] | lidx[32][32]
    __shared__ float taus[32];
    __shared__ int   lcnt[32];

    const bf16x8* kh8 = (const bf16x8*)khf_hi;
    const bf16x8* kl8 = (const bf16x8*)khf_lo;

    // Preload A-frags: 2 m-tiles x 2 k-chunks, hi+lo
    bf16x8 Ah[2][2], Al[2][2];
#pragma unroll
    for (int mt = 0; mt < 2; ++mt)
#pragma unroll
        for (int c = 0; c < 2; ++c) {
            size_t off = ((size_t)h * N_RNA + r0 + mt * 16 + n) * 64 + c * 32 + quad * 8;
            Ah[mt][c] = *(const bf16x8*)(qhi + off);
            Al[mt][c] = *(const bf16x8*)(qlo + off);
        }

    float mx[2][4];
#pragma unroll
    for (int mt = 0; mt < 2; ++mt)
#pragma unroll
        for (int i = 0; i < 4; ++i) mx[mt][i] = 0.f;

    // ---------------- phase A: approximate (hi*hi) bucket maxes ----------------
#pragma unroll 2
    for (int t = 0; t < 16; ++t) {
        int at = at0 + t;
        size_t bidx = ((size_t)hbase + at) * 128 + lane;
        bf16x8 Bh0 = kh8[bidx];
        bf16x8 Bh1 = kh8[bidx + 64];
        unsigned int bw = bits2[((size_t)rt64 * N_ATAC + at * 16 + n) * 2 + word];

        f32x4 S[2];
#pragma unroll
        for (int mt = 0; mt < 2; ++mt) {
            f32x4 s = {0.f, 0.f, 0.f, 0.f};
            s = mfma16(Ah[mt][0], Bh0, s);
            s = mfma16(Ah[mt][1], Bh1, s);
            S[mt] = s;
        }
#pragma unroll
        for (int mt = 0; mt < 2; ++mt) {
            unsigned int sh = bw >> ((mt << 4) + q4);
#pragma unroll
            for (int i = 0; i < 4; ++i) {
                float v = ((sh >> i) & 1) ? S[mt][i] : 0.f;
                mx[mt][i] = fmaxf(mx[mt][i], v);
            }
        }
    }

    {
        int b = w * 16 + n;
#pragma unroll
        for (int mt = 0; mt < 2; ++mt)
#pragma unroll
            for (int i = 0; i < 4; ++i) smem[(mt * 16 + q4 + i) * 65 + b] = mx[mt][i];
    }
    __syncthreads();
    if (tid < 32) {
        int row = tid;
        float t10 = 0.f;
        for (int pass = 0; pass < 10; ++pass) {
            float best = -1.f; int bj = 0;
            for (int j = 0; j < 64; ++j) {
                float v = smem[row * 65 + j];
                if (v > best) { best = v; bj = j; }
            }
            smem[row * 65 + bj] = -1.f;
            t10 = best;
        }
        taus[row] = t10 - TAU_EPS;
    } else if (tid < 64) {
        lcnt[tid - 32] = 0;
    }
    __syncthreads();

    float tau[2][4];
#pragma unroll
    for (int mt = 0; mt < 2; ++mt)
#pragma unroll
        for (int i = 0; i < 4; ++i) tau[mt][i] = taus[mt * 16 + q4 + i];

    float* lval = smem;                 // [32][CAP]
    int*   lidx = (int*)(smem + 1024);  // [32][CAP]

    // ---------------- phase B: exact scores, collect survivors ----------------
#pragma unroll 2
    for (int t = 0; t < 16; ++t) {
        int at = at0 + t;
        size_t bidx = ((size_t)hbase + at) * 128 + lane;
        bf16x8 Bh0 = kh8[bidx];
        bf16x8 Bh1 = kh8[bidx + 64];
        bf16x8 Bl0 = kl8[bidx];
        bf16x8 Bl1 = kl8[bidx + 64];
        unsigned int bw = bits2[((size_t)rt64 * N_ATAC + at * 16 + n) * 2 + word];

        f32x4 S[2];
#pragma unroll
        for (int mt = 0; mt < 2; ++mt) {
            f32x4 s = {0.f, 0.f, 0.f, 0.f};
            s = mfma16(Ah[mt][0], Bh0, s);
            s = mfma16(Ah[mt][1], Bh1, s);
            s = mfma16(Ah[mt][0], Bl0, s);
            s = mfma16(Ah[mt][1], Bl1, s);
            s = mfma16(Al[mt][0], Bh0, s);
            s = mfma16(Al[mt][1], Bh1, s);
            S[mt] = s;
        }
        int a16 = at * 16 + n;
#pragma unroll
        for (int mt = 0; mt < 2; ++mt) {
            unsigned int sh = bw >> ((mt << 4) + q4);
#pragma unroll
            for (int i = 0; i < 4; ++i) {
                if (((sh >> i) & 1) && S[mt][i] >= tau[mt][i]) {
                    int row = mt * 16 + q4 + i;
                    int pos = atomicAdd(&lcnt[row], 1);
                    if (pos < CAP) { lval[row * CAP + pos] = S[mt][i]; lidx[row * CAP + pos] = a16; }
                }
            }
        }
    }
    __syncthreads();

    // bulk write: block exclusively owns slot ((h*4096 + r)*8 + chunk)
    if (tid < 32) {
        int c = lcnt[tid]; if (c > CAP) c = CAP;
        scnt[((size_t)h * N_RNA + r0 + tid) * NCHUNK + chunk] = c;
    }
    {
        int row = tid >> 3, j0 = tid & 7;
        int c = lcnt[row]; if (c > CAP) c = CAP;
        size_t slot = ((size_t)h * N_RNA + r0 + row) * NCHUNK + chunk;
        for (int j = j0; j < c; j += 8) {
            sval[slot * CAP + j] = lval[row * CAP + j];
            sidx[slot * CAP + j] = lidx[row * CAP + j];
        }
    }
}

// ---------------------------------------------------------------- K2: fused finalize + gather + scatter
__global__ __launch_bounds__(256) void fin_agg(
    const int* __restrict__ scnt, const float* __restrict__ sval, const int* __restrict__ sidx,
    const float* __restrict__ v_a, const float* __restrict__ v_r,
    float* __restrict__ rna_agg, float* __restrict__ atac_agg) {
    int wid = threadIdx.x >> 6, lane = threadIdx.x & 63;
    int p = blockIdx.x * 4 + wid;          // (h*4096 + r)
    int h = p >> 12, r = p & 4095;
    size_t sbase = (size_t)p * NCHUNK;

    float val[4]; int aidx[4];
#pragma unroll
    for (int j = 0; j < 4; ++j) {
        int e = j * 64 + lane;
        int chunk = e >> 5, pos = e & 31;
        int c = scnt[sbase + chunk];
        size_t sl = (sbase + chunk) * CAP + pos;
        bool ok = pos < c;
        val[j] = ok ? sval[sl] : NEG_INF;
        aidx[j] = ok ? sidx[sl] : 0;
    }

    float sv[10]; int si[10];
#pragma unroll
    for (int s = 0; s < 10; ++s) {
        float bv = val[0]; int bj = 0;
#pragma unroll
        for (int j = 1; j < 4; ++j) if (val[j] > bv) { bv = val[j]; bj = j; }
        int bmeta = (bj << 6) | lane;
#pragma unroll
        for (int off = 32; off >= 1; off >>= 1) {
            float ov = __shfl_xor(bv, off);
            int om = __shfl_xor(bmeta, off);
            if (ov > bv || (ov == bv && om < bmeta)) { bv = ov; bmeta = om; }
        }
        int wj = bmeta >> 6, wl = bmeta & 63;
        if (lane == wl) {
#pragma unroll
            for (int j = 0; j < 4; ++j) if (j == wj) val[j] = NEG_INF;
        }
        int av = aidx[0];
#pragma unroll
        for (int j = 1; j < 4; ++j) if (wj == j) av = aidx[j];
        sv[s] = bv;
        si[s] = __shfl(av, wl);
    }

    float wgt[10]; float sum = 0.f; float sg[10];
#pragma unroll
    for (int s = 0; s < 10; ++s) {
        sg[s] = 1.0f / (1.0f + expf(-sv[s]));
        float es = expf(sg[s]);
        wgt[s] = es;
        sum += es;
    }
    float inv = 1.0f / sum;
#pragma unroll
    for (int s = 0; s < 10; ++s) {
        wgt[s] *= inv;
        if (!(sg[s] > 0.8f)) wgt[s] = 0.f;
    }

    float acc = 0.f;
#pragma unroll
    for (int s = 0; s < 10; ++s) {
        float vv = v_a[(size_t)si[s] * HID + h * 64 + lane];
        acc += wgt[s] * vv;
    }
    rna_agg[(size_t)r * HID + h * 64 + lane] = acc;

    float vr = v_r[(size_t)r * HID + h * 64 + lane];
#pragma unroll
    for (int s = 0; s < 10; ++s) {
        if (wgt[s] != 0.f) {
            atomicAdd(&atac_agg[(size_t)si[s] * HID + h * 64 + lane], wgt[s] * vr);
        }
    }
}

// ---------------------------------------------------------------- K3: out = [Agg|X] @ [W1;W2] + bias, LDS-tiled
__global__ __launch_bounds__(256) void out_gemm(
    const float* __restrict__ rna_agg, const float* __restrict__ x_rna,
    const float* __restrict__ Wr1, const float* __restrict__ Wr2, const float* __restrict__ brf,
    const float* __restrict__ atac_agg, const float* __restrict__ x_atac,
    const float* __restrict__ Wa1, const float* __restrict__ Wa2, const float* __restrict__ baf,
    float* __restrict__ out_r, float* __restrict__ out_a) {
    __shared__ __align__(16) float x_s[32][33];
    __shared__ __align__(16) float w_s[32][128];
    int bx = blockIdx.x;
    const float *A, *X, *W1, *W2, *bias; float* C;
    int r0;
    if (bx < 128) { A = rna_agg; X = x_rna; W1 = Wr1; W2 = Wr2; bias = brf; C = out_r; r0 = bx * 32; }
    else { A = atac_agg; X = x_atac; W1 = Wa1; W2 = Wa2; bias = baf; C = out_a; r0 = (bx - 128) * 32; }
    int tid = threadIdx.x;
    int rg = tid >> 4, cg = tid & 15;

    float acc[2][8];
#pragma unroll
    for (int i = 0; i < 2; ++i)
#pragma unroll
        for (int j = 0; j < 8; ++j) acc[i][j] = 0.f;

    for (int k0 = 0; k0 < 384; k0 += 32) {
        __syncthreads();
        {
            int rr = tid >> 3, kq = tid & 7;
            float4 v;
            if (k0 < 128) v = *(const float4*)&A[(size_t)(r0 + rr) * HID + k0 + kq * 4];
            else          v = *(const float4*)&X[(size_t)(r0 + rr) * IN_C + (k0 - 128) + kq * 4];
            x_s[rr][kq * 4 + 0] = v.x; x_s[rr][kq * 4 + 1] = v.y;
            x_s[rr][kq * 4 + 2] = v.z; x_s[rr][kq * 4 + 3] = v.w;
        }
        for (int i4 = tid; i4 < 1024; i4 += 256) {
            int kk = i4 >> 5, cq = i4 & 31;
            float4 v;
            if (k0 < 128) v = *(const float4*)&W1[(size_t)(k0 + kk) * HID + cq * 4];
            else          v = *(const float4*)&W2[(size_t)(k0 - 128 + kk) * HID + cq * 4];
            *(float4*)&w_s[kk][cq * 4] = v;
        }
        __syncthreads();
#pragma unroll 8
        for (int kk = 0; kk < 32; ++kk) {
            float x0 = x_s[rg * 2 + 0][kk], x1 = x_s[rg * 2 + 1][kk];
            float4 wa = *(const float4*)&w_s[kk][cg * 4];
            float4 wb = *(const float4*)&w_s[kk][64 + cg * 4];
            acc[0][0] += x0 * wa.x; acc[0][1] += x0 * wa.y; acc[0][2] += x0 * wa.z; acc[0][3] += x0 * wa.w;
            acc[0][4] += x0 * wb.x; acc[0][5] += x0 * wb.y; acc[0][6] += x0 * wb.z; acc[0][7] += x0 * wb.w;
            acc[1][0] += x1 * wa.x; acc[1][1] += x1 * wa.y; acc[1][2] += x1 * wa.z; acc[1][3] += x1 * wa.w;
            acc[1][4] += x1 * wb.x; acc[1][5] += x1 * wb.y; acc[1][6] += x1 * wb.z; acc[1][7] += x1 * wb.w;
        }
    }
    float bv[8];
#pragma unroll
    for (int j = 0; j < 8; ++j) {
        int c = (j < 4) ? (cg * 4 + j) : (64 + cg * 4 + (j - 4));
        bv[j] = bias[c];
    }
#pragma unroll
    for (int i = 0; i < 2; ++i) {
        int r = r0 + rg * 2 + i;
        float4 oa = make_float4(acc[i][0] + bv[0], acc[i][1] + bv[1], acc[i][2] + bv[2], acc[i][3] + bv[3]);
        float4 ob = make_float4(acc[i][4] + bv[4], acc[i][5] + bv[5], acc[i][6] + bv[6], acc[i][7] + bv[7]);
        *(float4*)&C[(size_t)r * HID + cg * 4] = oa;
        *(float4*)&C[(size_t)r * HID + 64 + cg * 4] = ob;
    }
}

// ---------------------------------------------------------------- launch
extern "C" void kernel_launch(void* const* d_in, const int* in_sizes, int n_in,
                              void* d_out, int out_size, void* d_ws, size_t ws_size,
                              hipStream_t stream) {
    const float* x_rna = (const float*)d_in[0];
    const float* x_atac = (const float*)d_in[1];
    const float* mask = (const float*)d_in[2];
    const float* Wq = (const float*)d_in[3];  const float* bq = (const float*)d_in[4];
    const float* Wk = (const float*)d_in[5];  const float* bk = (const float*)d_in[6];
    const float* Wvr = (const float*)d_in[7]; const float* bvr = (const float*)d_in[8];
    const float* Wva = (const float*)d_in[9]; const float* bva = (const float*)d_in[10];
    const float* Wor = (const float*)d_in[11]; const float* bor = (const float*)d_in[12];
    const float* Woa = (const float*)d_in[13]; const float* boa = (const float*)d_in[14];
    const float* Wsr = (const float*)d_in[15]; const float* bsr = (const float*)d_in[16];
    const float* Wsa = (const float*)d_in[17]; const float* bsa = (const float*)d_in[18];
    const float* Wdr = (const float*)d_in[19]; const float* bdr = (const float*)d_in[20];
    const float* Wda = (const float*)d_in[21]; const float* bda = (const float*)d_in[22];

    float* out_r = (float*)d_out;
    float* out_a = out_r + N_RNA * HID;

    float* ws = (float*)d_ws;
    unsigned short* qhi = (unsigned short*)ws;            // 2*4096*64 us
    unsigned short* qlo = qhi + 524288;
    unsigned short* khf_hi = qlo + 524288;                // 2*8192*64 us (frag layout)
    unsigned short* khf_lo = khf_hi + 1048576;
    unsigned int* bits2 = (unsigned int*)(ws + 1572864);  // 64*8192*2 uint
    float* v_r = ws + 1572864 + 1048576;                  // 4096x128
    float* v_a = v_r + 524288;                            // 8192x128
    float* Wr1 = v_a + 1048576;                           // 128x128
    float* Wr2 = Wr1 + 16384;                             // 256x128
    float* brf = Wr2 + 32768;                             // 128
    float* Wa1 = brf + 128;                               // 128x128
    float* Wa2 = Wa1 + 16384;                             // 256x128
    float* baf = Wa2 + 32768;                             // 128
    int* scnt = (int*)(baf + 128);                        // 8192*8 ints
    float* sval = (float*)scnt + 65536;                   // 65536*32
    int* sidx = (int*)(sval + 2097152);                   // 65536*32
    float* rna_agg = (float*)sidx + 2097152;              // 4096x128
    float* atac_agg = rna_agg + 524288;                   // 8192x128

    hipLaunchKernelGGL(prep_all, dim3(1538), dim3(256), 0, stream,
                       mask, bits2, atac_agg,
                       Wor, bor, Woa, boa, Wsr, bsr, Wsa, bsa, Wdr, bdr, Wda, bda,
                       Wr1, Wr2, brf, Wa1, Wa2, baf,
                       x_rna, x_atac, Wq, bq, Wk, bk, Wvr, bvr, Wva, bva,
                       qhi, qlo, khf_hi, khf_lo, v_r, v_a);
    hipLaunchKernelGGL(attn2, dim3(16, 128), dim3(256), 0, stream,
                       qhi, qlo, khf_hi, khf_lo, bits2, scnt, sval, sidx);
    hipLaunchKernelGGL(fin_agg, dim3(2048), dim3(256), 0, stream,
                       scnt, sval, sidx, v_a, v_r, rna_agg, atac_agg);
    hipLaunchKernelGGL(out_gemm, dim3(384), dim3(256), 0, stream,
                       rna_agg, x_rna, Wr1, Wr2, brf,
                       atac_agg, x_atac, Wa1, Wa2, baf, out_r, out_a);
}

// Round 9
// 413.226 us; speedup vs baseline: 1.3629x; 1.0288x over previous
//
#include <hip/hip_runtime.h>
#include <math.h>

#define N_RNA 4096
#define N_ATAC 8192
#define IN_C 256
#define HID 128
#define NH 2
#define TOPK 10
#define CAP 32
#define NCHUNK 8
#define TAU_EPS 0.12f
#define NEG_INF -3.402823466e38f

typedef __attribute__((ext_vector_type(8))) short bf16x8;
typedef __attribute__((ext_vector_type(4))) float f32x4;

static __device__ __forceinline__ f32x4 mfma16(bf16x8 a, bf16x8 b, f32x4 c) {
    return __builtin_amdgcn_mfma_f32_16x16x32_bf16(a, b, c, 0, 0, 0);
}

static __device__ __forceinline__ unsigned short f2bf(float f) {
    unsigned int u = __float_as_uint(f);
    unsigned int r = (u + 0x7fffu + ((u >> 16) & 1u)) >> 16;   // RNE
    return (unsigned short)r;
}
static __device__ __forceinline__ float bf2f(unsigned short h) {
    return __uint_as_float(((unsigned int)h) << 16);
}

// ---------------------------------------------------------------- K0: prep_all (block-ranged)
// [0,768): projections (32-row tiles).  [768,1792): mask->bits2 (float2, 2a/thr).
// [1792,2048): zero atac_agg.  [2048,2434): fuse weights.
__global__ __launch_bounds__(256) void prep_all(
    const float* __restrict__ mask, unsigned int* __restrict__ bits2,
    float* __restrict__ atac_agg,
    const float* __restrict__ Wor, const float* __restrict__ bor,
    const float* __restrict__ Woa, const float* __restrict__ boa,
    const float* __restrict__ Wsr, const float* __restrict__ bsr,
    const float* __restrict__ Wsa, const float* __restrict__ bsa,
    const float* __restrict__ Wdr, const float* __restrict__ bdr,
    const float* __restrict__ Wda, const float* __restrict__ bda,
    float* __restrict__ Wr1, float* __restrict__ Wr2, float* __restrict__ br,
    float* __restrict__ Wa1, float* __restrict__ Wa2, float* __restrict__ ba,
    const float* __restrict__ x_rna, const float* __restrict__ x_atac,
    const float* __restrict__ Wq, const float* __restrict__ bq,
    const float* __restrict__ Wk, const float* __restrict__ bk,
    const float* __restrict__ Wvr, const float* __restrict__ bvr,
    const float* __restrict__ Wva, const float* __restrict__ bva,
    unsigned short* __restrict__ qhi, unsigned short* __restrict__ qlo,
    unsigned short* __restrict__ khf_hi, unsigned short* __restrict__ khf_lo,
    float* __restrict__ v_r, float* __restrict__ v_a) {
    __shared__ __align__(16) float x_s[32][33];
    __shared__ __align__(16) float w_s[32][128];
    int bx = blockIdx.x;
    int tid = threadIdx.x;

    if (bx >= 768 && bx < 1792) {                 // ---- mask -> bits2, float2 (2 a/thread)
        int e = bx - 768;
        int rt = e >> 4, ac = e & 15;
        int a0 = ac * 512 + tid * 2;
        int r0 = rt * 64;
        unsigned int w0[2] = {0, 0}, w1[2] = {0, 0};
#pragma unroll 8
        for (int rr = 0; rr < 32; ++rr) {
            float2 m0 = *(const float2*)&mask[(size_t)(r0 + rr) * N_ATAC + a0];
            float2 m1 = *(const float2*)&mask[(size_t)(r0 + 32 + rr) * N_ATAC + a0];
            w0[0] |= ((m0.x > 0.5f) ? 1u : 0u) << rr;
            w0[1] |= ((m0.y > 0.5f) ? 1u : 0u) << rr;
            w1[0] |= ((m1.x > 0.5f) ? 1u : 0u) << rr;
            w1[1] |= ((m1.y > 0.5f) ? 1u : 0u) << rr;
        }
        uint4 o = make_uint4(w0[0], w1[0], w0[1], w1[1]);
        *(uint4*)&bits2[((size_t)rt * N_ATAC + a0) * 2] = o;
        return;
    }
    if (bx >= 1792 && bx < 2048) {                // ---- zero atac_agg (64 B/thread)
        size_t i = ((size_t)(bx - 1792) * 256 + tid) * 16;
        float4 z = make_float4(0.f, 0.f, 0.f, 0.f);
        *(float4*)&atac_agg[i] = z;
        *(float4*)&atac_agg[i + 4] = z;
        *(float4*)&atac_agg[i + 8] = z;
        *(float4*)&atac_agg[i + 12] = z;
        return;
    }
    if (bx >= 2048) {                             // ---- fuse weights
        int f = (bx - 2048) * 256 + tid;
        if (f < 16384) {
            int i = f >> 7, j = f & 127; float s = 0.f;
            for (int t = 0; t < 128; ++t) s += Wor[i * 128 + t] * Wdr[t * 128 + j];
            Wr1[f] = s;
        } else if (f < 49152) {
            int e = f - 16384; int i = e >> 7, j = e & 127; float s = 0.f;
            for (int t = 0; t < 128; ++t) s += Wsr[i * 128 + t] * Wdr[(128 + t) * 128 + j];
            Wr2[e] = s;
        } else if (f < 65536) {
            int e = f - 49152; int i = e >> 7, j = e & 127; float s = 0.f;
            for (int t = 0; t < 128; ++t) s += Woa[i * 128 + t] * Wda[t * 128 + j];
            Wa1[e] = s;
        } else if (f < 98304) {
            int e = f - 65536; int i = e >> 7, j = e & 127; float s = 0.f;
            for (int t = 0; t < 128; ++t) s += Wsa[i * 128 + t] * Wda[(128 + t) * 128 + j];
            Wa2[e] = s;
        } else if (f < 98432) {
            int j = f - 98304; float s = bdr[j];
            for (int t = 0; t < 128; ++t) s += bor[t] * Wdr[t * 128 + j] + bsr[t] * Wdr[(128 + t) * 128 + j];
            br[j] = s;
        } else if (f < 98560) {
            int j = f - 98432; float s = bda[j];
            for (int t = 0; t < 128; ++t) s += boa[t] * Wda[t * 128 + j] + bsa[t] * Wda[(128 + t) * 128 + j];
            ba[j] = s;
        }
        return;
    }

    // ---- projections (blocks [0,768)), 32-row tiles
    int e = bx;
    int cfg, rblk;
    if (e < 128)      { cfg = 0; rblk = e; }
    else if (e < 256) { cfg = 1; rblk = e - 128; }
    else if (e < 512) { cfg = 2; rblk = e - 256; }
    else              { cfg = 3; rblk = e - 512; }
    const float *X, *W, *B;
    if (cfg == 0)      { X = x_rna;  W = Wq;  B = bq;  }
    else if (cfg == 1) { X = x_rna;  W = Wvr; B = bvr; }
    else if (cfg == 2) { X = x_atac; W = Wk;  B = bk;  }
    else               { X = x_atac; W = Wva; B = bva; }
    int r0 = rblk * 32;
    int rg = tid >> 4, cg = tid & 15;

    float acc[2][8];
#pragma unroll
    for (int i = 0; i < 2; ++i)
#pragma unroll
        for (int j = 0; j < 8; ++j) acc[i][j] = 0.f;

    for (int k0 = 0; k0 < IN_C; k0 += 32) {
        __syncthreads();
        {   // stage X 32x32
            int rr = tid >> 3, kq = tid & 7;
            float4 v = *(const float4*)&X[(size_t)(r0 + rr) * IN_C + k0 + kq * 4];
            x_s[rr][kq * 4 + 0] = v.x; x_s[rr][kq * 4 + 1] = v.y;
            x_s[rr][kq * 4 + 2] = v.z; x_s[rr][kq * 4 + 3] = v.w;
        }
        for (int i4 = tid; i4 < 1024; i4 += 256) {   // stage W 32x128
            int kk = i4 >> 5, cq = i4 & 31;
            float4 v = *(const float4*)&W[(size_t)(k0 + kk) * HID + cq * 4];
            *(float4*)&w_s[kk][cq * 4] = v;
        }
        __syncthreads();
#pragma unroll 8
        for (int kk = 0; kk < 32; ++kk) {
            float x0 = x_s[rg * 2 + 0][kk], x1 = x_s[rg * 2 + 1][kk];
            float4 wa = *(const float4*)&w_s[kk][cg * 4];
            float4 wb = *(const float4*)&w_s[kk][64 + cg * 4];
            acc[0][0] += x0 * wa.x; acc[0][1] += x0 * wa.y; acc[0][2] += x0 * wa.z; acc[0][3] += x0 * wa.w;
            acc[0][4] += x0 * wb.x; acc[0][5] += x0 * wb.y; acc[0][6] += x0 * wb.z; acc[0][7] += x0 * wb.w;
            acc[1][0] += x1 * wa.x; acc[1][1] += x1 * wa.y; acc[1][2] += x1 * wa.z; acc[1][3] += x1 * wa.w;
            acc[1][4] += x1 * wb.x; acc[1][5] += x1 * wb.y; acc[1][6] += x1 * wb.z; acc[1][7] += x1 * wb.w;
        }
    }
    float bv[8];
#pragma unroll
    for (int j = 0; j < 8; ++j) {
        int c = (j < 4) ? (cg * 4 + j) : (64 + cg * 4 + (j - 4));
        bv[j] = B[c];
    }
    if (cfg == 0 || cfg == 2) {
#pragma unroll
        for (int i = 0; i < 2; ++i) {
            int r = r0 + rg * 2 + i;
            float va[8];
#pragma unroll
            for (int j = 0; j < 8; ++j) va[j] = acc[i][j] + bv[j];
            ushort4 h0, l0, h1, l1;
            h0.x = f2bf(va[0]); h0.y = f2bf(va[1]); h0.z = f2bf(va[2]); h0.w = f2bf(va[3]);
            h1.x = f2bf(va[4]); h1.y = f2bf(va[5]); h1.z = f2bf(va[6]); h1.w = f2bf(va[7]);
            l0.x = f2bf(va[0] - bf2f(h0.x)); l0.y = f2bf(va[1] - bf2f(h0.y));
            l0.z = f2bf(va[2] - bf2f(h0.z)); l0.w = f2bf(va[3] - bf2f(h0.w));
            l1.x = f2bf(va[4] - bf2f(h1.x)); l1.y = f2bf(va[5] - bf2f(h1.y));
            l1.z = f2bf(va[6] - bf2f(h1.z)); l1.w = f2bf(va[7] - bf2f(h1.w));
            if (cfg == 0) {
                size_t o0 = (size_t)r * 64 + cg * 4;
                size_t o1 = (size_t)(N_RNA + r) * 64 + cg * 4;
                *(ushort4*)&qhi[o0] = h0; *(ushort4*)&qhi[o1] = h1;
                *(ushort4*)&qlo[o0] = l0; *(ushort4*)&qlo[o1] = l1;
            } else {
                int at = r >> 4, n = r & 15;
                int kc = cg >> 1, ee = (cg & 1) * 4;
                size_t o0 = ((size_t)(at) * 8 + kc) * 128 + n * 8 + ee;
                size_t o1 = ((size_t)(512 + at) * 8 + kc) * 128 + n * 8 + ee;
                *(ushort4*)&khf_hi[o0] = h0; *(ushort4*)&khf_hi[o1] = h1;
                *(ushort4*)&khf_lo[o0] = l0; *(ushort4*)&khf_lo[o1] = l1;
            }
        }
    } else {
        float* C = (cfg == 1) ? v_r : v_a;
#pragma unroll
        for (int i = 0; i < 2; ++i) {
            int r = r0 + rg * 2 + i;
            float4 oa = make_float4(acc[i][0] + bv[0], acc[i][1] + bv[1], acc[i][2] + bv[2], acc[i][3] + bv[3]);
            float4 ob = make_float4(acc[i][4] + bv[4], acc[i][5] + bv[5], acc[i][6] + bv[6], acc[i][7] + bv[7]);
            *(float4*)&C[(size_t)r * HID + cg * 4] = oa;
            *(float4*)&C[(size_t)r * HID + 64 + cg * 4] = ob;
        }
    }
}

// ---------------------------------------------------------------- K1: two-phase MFMA attention
// grid (16 = h*8+chunk, 128 rtiles of 32 rows), block 256 (4 waves).
// blockIdx.x fastest -> linear%8 = chunk pins each a-chunk's K+bits slice (~1 MB)
// to one XCD L2; q streams via L3.  32-row body fits 64 VGPR (no spill).
__global__ __launch_bounds__(256, 4) void attn2(
    const unsigned short* __restrict__ qhi, const unsigned short* __restrict__ qlo,
    const unsigned short* __restrict__ khf_hi, const unsigned short* __restrict__ khf_lo,
    const unsigned int* __restrict__ bits2,
    int* __restrict__ scnt, float* __restrict__ sval, int* __restrict__ sidx) {
    int hq = blockIdx.x; int h = hq >> 3, chunk = hq & 7;
    int rt = blockIdx.y; int r0 = rt * 32;
    int tid = threadIdx.x;
    int w = tid >> 6, lane = tid & 63;
    int n = lane & 15, quad = lane >> 4;
    int q4 = quad * 4;
    int at0 = chunk * 64 + w * 16;          // a-tile base (16 a per tile)
    int hbase = h * 512;
    int rt64 = rt >> 1, word = rt & 1;

    __shared__ __align__(16) float smem[32 * 65];   // bmax [32][65]; reused: lval[32][32] | lidx[32][32]
    __shared__ float taus[32];
    __shared__ int   lcnt[32];

    const bf16x8* kh8 = (const bf16x8*)khf_hi;
    const bf16x8* kl8 = (const bf16x8*)khf_lo;

    // Preload A-frags: 2 m-tiles x 2 k-chunks, hi+lo
    bf16x8 Ah[2][2], Al[2][2];
#pragma unroll
    for (int mt = 0; mt < 2; ++mt)
#pragma unroll
        for (int c = 0; c < 2; ++c) {
            size_t off = ((size_t)h * N_RNA + r0 + mt * 16 + n) * 64 + c * 32 + quad * 8;
            Ah[mt][c] = *(const bf16x8*)(qhi + off);
            Al[mt][c] = *(const bf16x8*)(qlo + off);
        }

    float mx[2][4];
#pragma unroll
    for (int mt = 0; mt < 2; ++mt)
#pragma unroll
        for (int i = 0; i < 4; ++i) mx[mt][i] = 0.f;

    // ---------------- phase A: approximate (hi*hi) bucket maxes ----------------
#pragma unroll 2
    for (int t = 0; t < 16; ++t) {
        int at = at0 + t;
        size_t bidx = ((size_t)hbase + at) * 128 + lane;
        bf16x8 Bh0 = kh8[bidx];
        bf16x8 Bh1 = kh8[bidx + 64];
        unsigned int bw = bits2[((size_t)rt64 * N_ATAC + at * 16 + n) * 2 + word];

        f32x4 S[2];
#pragma unroll
        for (int mt = 0; mt < 2; ++mt) {
            f32x4 s = {0.f, 0.f, 0.f, 0.f};
            s = mfma16(Ah[mt][0], Bh0, s);
            s = mfma16(Ah[mt][1], Bh1, s);
            S[mt] = s;
        }
#pragma unroll
        for (int mt = 0; mt < 2; ++mt) {
            unsigned int sh = bw >> ((mt << 4) + q4);
#pragma unroll
            for (int i = 0; i < 4; ++i) {
                float v = ((sh >> i) & 1) ? S[mt][i] : 0.f;
                mx[mt][i] = fmaxf(mx[mt][i], v);
            }
        }
    }

    {
        int b = w * 16 + n;
#pragma unroll
        for (int mt = 0; mt < 2; ++mt)
#pragma unroll
            for (int i = 0; i < 4; ++i) smem[(mt * 16 + q4 + i) * 65 + b] = mx[mt][i];
    }
    __syncthreads();
    if (tid < 32) {
        int row = tid;
        float t10 = 0.f;
        for (int pass = 0; pass < 10; ++pass) {
            float best = -1.f; int bj = 0;
            for (int j = 0; j < 64; ++j) {
                float v = smem[row * 65 + j];
                if (v > best) { best = v; bj = j; }
            }
            smem[row * 65 + bj] = -1.f;
            t10 = best;
        }
        taus[row] = t10 - TAU_EPS;
    } else if (tid < 64) {
        lcnt[tid - 32] = 0;
    }
    __syncthreads();

    float tau[2][4];
#pragma unroll
    for (int mt = 0; mt < 2; ++mt)
#pragma unroll
        for (int i = 0; i < 4; ++i) tau[mt][i] = taus[mt * 16 + q4 + i];

    float* lval = smem;                 // [32][CAP]
    int*   lidx = (int*)(smem + 1024);  // [32][CAP]

    // ---------------- phase B: exact scores, collect survivors ----------------
#pragma unroll 2
    for (int t = 0; t < 16; ++t) {
        int at = at0 + t;
        size_t bidx = ((size_t)hbase + at) * 128 + lane;
        bf16x8 Bh0 = kh8[bidx];
        bf16x8 Bh1 = kh8[bidx + 64];
        bf16x8 Bl0 = kl8[bidx];
        bf16x8 Bl1 = kl8[bidx + 64];
        unsigned int bw = bits2[((size_t)rt64 * N_ATAC + at * 16 + n) * 2 + word];

        f32x4 S[2];
#pragma unroll
        for (int mt = 0; mt < 2; ++mt) {
            f32x4 s = {0.f, 0.f, 0.f, 0.f};
            s = mfma16(Ah[mt][0], Bh0, s);
            s = mfma16(Ah[mt][1], Bh1, s);
            s = mfma16(Ah[mt][0], Bl0, s);
            s = mfma16(Ah[mt][1], Bl1, s);
            s = mfma16(Al[mt][0], Bh0, s);
            s = mfma16(Al[mt][1], Bh1, s);
            S[mt] = s;
        }
        int a16 = at * 16 + n;
#pragma unroll
        for (int mt = 0; mt < 2; ++mt) {
            unsigned int sh = bw >> ((mt << 4) + q4);
#pragma unroll
            for (int i = 0; i < 4; ++i) {
                if (((sh >> i) & 1) && S[mt][i] >= tau[mt][i]) {
                    int row = mt * 16 + q4 + i;
                    int pos = atomicAdd(&lcnt[row], 1);
                    if (pos < CAP) { lval[row * CAP + pos] = S[mt][i]; lidx[row * CAP + pos] = a16; }
                }
            }
        }
    }
    __syncthreads();

    // bulk write: block exclusively owns slot ((h*4096 + r)*8 + chunk)
    if (tid < 32) {
        int c = lcnt[tid]; if (c > CAP) c = CAP;
        scnt[((size_t)h * N_RNA + r0 + tid) * NCHUNK + chunk] = c;
    }
    {
        int row = tid >> 3, j0 = tid & 7;
        int c = lcnt[row]; if (c > CAP) c = CAP;
        size_t slot = ((size_t)h * N_RNA + r0 + row) * NCHUNK + chunk;
        for (int j = j0; j < c; j += 8) {
            sval[slot * CAP + j] = lval[row * CAP + j];
            sidx[slot * CAP + j] = lidx[row * CAP + j];
        }
    }
}

// ---------------------------------------------------------------- K2: fused finalize + gather + scatter
__global__ __launch_bounds__(256) void fin_agg(
    const int* __restrict__ scnt, const float* __restrict__ sval, const int* __restrict__ sidx,
    const float* __restrict__ v_a, const float* __restrict__ v_r,
    float* __restrict__ rna_agg, float* __restrict__ atac_agg) {
    int wid = threadIdx.x >> 6, lane = threadIdx.x & 63;
    int p = blockIdx.x * 4 + wid;          // (h*4096 + r)
    int h = p >> 12, r = p & 4095;
    size_t sbase = (size_t)p * NCHUNK;

    float val[4]; int aidx[4];
#pragma unroll
    for (int j = 0; j < 4; ++j) {
        int e = j * 64 + lane;
        int chunk = e >> 5, pos = e & 31;
        int c = scnt[sbase + chunk];
        size_t sl = (sbase + chunk) * CAP + pos;
        bool ok = pos < c;
        val[j] = ok ? sval[sl] : NEG_INF;
        aidx[j] = ok ? sidx[sl] : 0;
    }

    float sv[10]; int si[10];
#pragma unroll
    for (int s = 0; s < 10; ++s) {
        float bv = val[0]; int bj = 0;
#pragma unroll
        for (int j = 1; j < 4; ++j) if (val[j] > bv) { bv = val[j]; bj = j; }
        int bmeta = (bj << 6) | lane;
#pragma unroll
        for (int off = 32; off >= 1; off >>= 1) {
            float ov = __shfl_xor(bv, off);
            int om = __shfl_xor(bmeta, off);
            if (ov > bv || (ov == bv && om < bmeta)) { bv = ov; bmeta = om; }
        }
        int wj = bmeta >> 6, wl = bmeta & 63;
        if (lane == wl) {
#pragma unroll
            for (int j = 0; j < 4; ++j) if (j == wj) val[j] = NEG_INF;
        }
        int av = aidx[0];
#pragma unroll
        for (int j = 1; j < 4; ++j) if (wj == j) av = aidx[j];
        sv[s] = bv;
        si[s] = __shfl(av, wl);
    }

    float wgt[10]; float sum = 0.f; float sg[10];
#pragma unroll
    for (int s = 0; s < 10; ++s) {
        sg[s] = 1.0f / (1.0f + expf(-sv[s]));
        float es = expf(sg[s]);
        wgt[s] = es;
        sum += es;
    }
    float inv = 1.0f / sum;
#pragma unroll
    for (int s = 0; s < 10; ++s) {
        wgt[s] *= inv;
        if (!(sg[s] > 0.8f)) wgt[s] = 0.f;
    }

    float acc = 0.f;
#pragma unroll
    for (int s = 0; s < 10; ++s) {
        float vv = v_a[(size_t)si[s] * HID + h * 64 + lane];
        acc += wgt[s] * vv;
    }
    rna_agg[(size_t)r * HID + h * 64 + lane] = acc;

    float vr = v_r[(size_t)r * HID + h * 64 + lane];
#pragma unroll
    for (int s = 0; s < 10; ++s) {
        if (wgt[s] != 0.f) {
            atomicAdd(&atac_agg[(size_t)si[s] * HID + h * 64 + lane], wgt[s] * vr);
        }
    }
}

// ---------------------------------------------------------------- K3: out = [Agg|X] @ [W1;W2] + bias, LDS-tiled
__global__ __launch_bounds__(256) void out_gemm(
    const float* __restrict__ rna_agg, const float* __restrict__ x_rna,
    const float* __restrict__ Wr1, const float* __restrict__ Wr2, const float* __restrict__ brf,
    const float* __restrict__ atac_agg, const float* __restrict__ x_atac,
    const float* __restrict__ Wa1, const float* __restrict__ Wa2, const float* __restrict__ baf,
    float* __restrict__ out_r, float* __restrict__ out_a) {
    __shared__ __align__(16) float x_s[32][33];
    __shared__ __align__(16) float w_s[32][128];
    int bx = blockIdx.x;
    const float *A, *X, *W1, *W2, *bias; float* C;
    int r0;
    if (bx < 128) { A = rna_agg; X = x_rna; W1 = Wr1; W2 = Wr2; bias = brf; C = out_r; r0 = bx * 32; }
    else { A = atac_agg; X = x_atac; W1 = Wa1; W2 = Wa2; bias = baf; C = out_a; r0 = (bx - 128) * 32; }
    int tid = threadIdx.x;
    int rg = tid >> 4, cg = tid & 15;

    float acc[2][8];
#pragma unroll
    for (int i = 0; i < 2; ++i)
#pragma unroll
        for (int j = 0; j < 8; ++j) acc[i][j] = 0.f;

    for (int k0 = 0; k0 < 384; k0 += 32) {
        __syncthreads();
        {
            int rr = tid >> 3, kq = tid & 7;
            float4 v;
            if (k0 < 128) v = *(const float4*)&A[(size_t)(r0 + rr) * HID + k0 + kq * 4];
            else          v = *(const float4*)&X[(size_t)(r0 + rr) * IN_C + (k0 - 128) + kq * 4];
            x_s[rr][kq * 4 + 0] = v.x; x_s[rr][kq * 4 + 1] = v.y;
            x_s[rr][kq * 4 + 2] = v.z; x_s[rr][kq * 4 + 3] = v.w;
        }
        for (int i4 = tid; i4 < 1024; i4 += 256) {
            int kk = i4 >> 5, cq = i4 & 31;
            float4 v;
            if (k0 < 128) v = *(const float4*)&W1[(size_t)(k0 + kk) * HID + cq * 4];
            else          v = *(const float4*)&W2[(size_t)(k0 - 128 + kk) * HID + cq * 4];
            *(float4*)&w_s[kk][cq * 4] = v;
        }
        __syncthreads();
#pragma unroll 8
        for (int kk = 0; kk < 32; ++kk) {
            float x0 = x_s[rg * 2 + 0][kk], x1 = x_s[rg * 2 + 1][kk];
            float4 wa = *(const float4*)&w_s[kk][cg * 4];
            float4 wb = *(const float4*)&w_s[kk][64 + cg * 4];
            acc[0][0] += x0 * wa.x; acc[0][1] += x0 * wa.y; acc[0][2] += x0 * wa.z; acc[0][3] += x0 * wa.w;
            acc[0][4] += x0 * wb.x; acc[0][5] += x0 * wb.y; acc[0][6] += x0 * wb.z; acc[0][7] += x0 * wb.w;
            acc[1][0] += x1 * wa.x; acc[1][1] += x1 * wa.y; acc[1][2] += x1 * wa.z; acc[1][3] += x1 * wa.w;
            acc[1][4] += x1 * wb.x; acc[1][5] += x1 * wb.y; acc[1][6] += x1 * wb.z; acc[1][7] += x1 * wb.w;
        }
    }
    float bv[8];
#pragma unroll
    for (int j = 0; j < 8; ++j) {
        int c = (j < 4) ? (cg * 4 + j) : (64 + cg * 4 + (j - 4));
        bv[j] = bias[c];
    }
#pragma unroll
    for (int i = 0; i < 2; ++i) {
        int r = r0 + rg * 2 + i;
        float4 oa = make_float4(acc[i][0] + bv[0], acc[i][1] + bv[1], acc[i][2] + bv[2], acc[i][3] + bv[3]);
        float4 ob = make_float4(acc[i][4] + bv[4], acc[i][5] + bv[5], acc[i][6] + bv[6], acc[i][7] + bv[7]);
        *(float4*)&C[(size_t)r * HID + cg * 4] = oa;
        *(float4*)&C[(size_t)r * HID + 64 + cg * 4] = ob;
    }
}

// ---------------------------------------------------------------- launch
extern "C" void kernel_launch(void* const* d_in, const int* in_sizes, int n_in,
                              void* d_out, int out_size, void* d_ws, size_t ws_size,
                              hipStream_t stream) {
    const float* x_rna = (const float*)d_in[0];
    const float* x_atac = (const float*)d_in[1];
    const float* mask = (const float*)d_in[2];
    const float* Wq = (const float*)d_in[3];  const float* bq = (const float*)d_in[4];
    const float* Wk = (const float*)d_in[5];  const float* bk = (const float*)d_in[6];
    const float* Wvr = (const float*)d_in[7]; const float* bvr = (const float*)d_in[8];
    const float* Wva = (const float*)d_in[9]; const float* bva = (const float*)d_in[10];
    const float* Wor = (const float*)d_in[11]; const float* bor = (const float*)d_in[12];
    const float* Woa = (const float*)d_in[13]; const float* boa = (const float*)d_in[14];
    const float* Wsr = (const float*)d_in[15]; const float* bsr = (const float*)d_in[16];
    const float* Wsa = (const float*)d_in[17]; const float* bsa = (const float*)d_in[18];
    const float* Wdr = (const float*)d_in[19]; const float* bdr = (const float*)d_in[20];
    const float* Wda = (const float*)d_in[21]; const float* bda = (const float*)d_in[22];

    float* out_r = (float*)d_out;
    float* out_a = out_r + N_RNA * HID;

    float* ws = (float*)d_ws;
    unsigned short* qhi = (unsigned short*)ws;            // 2*4096*64 us
    unsigned short* qlo = qhi + 524288;
    unsigned short* khf_hi = qlo + 524288;                // 2*8192*64 us (frag layout)
    unsigned short* khf_lo = khf_hi + 1048576;
    unsigned int* bits2 = (unsigned int*)(ws + 1572864);  // 64*8192*2 uint
    float* v_r = ws + 1572864 + 1048576;                  // 4096x128
    float* v_a = v_r + 524288;                            // 8192x128
    float* Wr1 = v_a + 1048576;                           // 128x128
    float* Wr2 = Wr1 + 16384;                             // 256x128
    float* brf = Wr2 + 32768;                             // 128
    float* Wa1 = brf + 128;                               // 128x128
    float* Wa2 = Wa1 + 16384;                             // 256x128
    float* baf = Wa2 + 32768;                             // 128
    int* scnt = (int*)(baf + 128);                        // 8192*8 ints
    float* sval = (float*)scnt + 65536;                   // 65536*32
    int* sidx = (int*)(sval + 2097152);                   // 65536*32
    float* rna_agg = (float*)sidx + 2097152;              // 4096x128
    float* atac_agg = rna_agg + 524288;                   // 8192x128

    hipLaunchKernelGGL(prep_all, dim3(2434), dim3(256), 0, stream,
                       mask, bits2, atac_agg,
                       Wor, bor, Woa, boa, Wsr, bsr, Wsa, bsa, Wdr, bdr, Wda, bda,
                       Wr1, Wr2, brf, Wa1, Wa2, baf,
                       x_rna, x_atac, Wq, bq, Wk, bk, Wvr, bvr, Wva, bva,
                       qhi, qlo, khf_hi, khf_lo, v_r, v_a);
    hipLaunchKernelGGL(attn2, dim3(16, 128), dim3(256), 0, stream,
                       qhi, qlo, khf_hi, khf_lo, bits2, scnt, sval, sidx);
    hipLaunchKernelGGL(fin_agg, dim3(2048), dim3(256), 0, stream,
                       scnt, sval, sidx, v_a, v_r, rna_agg, atac_agg);
    hipLaunchKernelGGL(out_gemm, dim3(384), dim3(256), 0, stream,
                       rna_agg, x_rna, Wr1, Wr2, brf,
                       atac_agg, x_atac, Wa1, Wa2, baf, out_r, out_a);
}